// Round 7
// baseline (2979.082 us; speedup 1.0000x reference)
//
#include <hip/hip_runtime.h>
#include <hip/hip_bf16.h>

#define HH 128   // hidden
#define EDD 64   // edge_dim
#define NLAYER 3
#define LN_EPS 1e-5f

typedef __attribute__((ext_vector_type(8))) __bf16 bf16x8;
typedef __attribute__((ext_vector_type(4))) float f32x4;

// ---------------------------------------------------------------------------
// CSR build (once per call; edge_index is layer-invariant)
// ---------------------------------------------------------------------------
__global__ __launch_bounds__(256) void hist_kernel(
    const int* __restrict__ dst, int* __restrict__ cnt, int E)
{
    for (int e = blockIdx.x * blockDim.x + threadIdx.x; e < E;
         e += gridDim.x * blockDim.x)
        atomicAdd(&cnt[dst[e]], 1);
}

__global__ __launch_bounds__(1024) void scan_kernel(
    const int* __restrict__ cnt, int* __restrict__ off, int N)
{
    __shared__ int ls[1024];
    const int t = threadIdx.x;
    const int C = (N + 1023) >> 10;
    const int lo = t * C;
    const int hi = min(lo + C, N);
    int sum = 0;
    for (int i = lo; i < hi; ++i) sum += cnt[i];
    ls[t] = sum;
    __syncthreads();
    for (int d = 1; d < 1024; d <<= 1) {
        int v = (t >= d) ? ls[t - d] : 0;
        __syncthreads();
        ls[t] += v;
        __syncthreads();
    }
    int excl = (t == 0) ? 0 : ls[t - 1];
    for (int i = lo; i < hi; ++i) { off[i] = excl; excl += cnt[i]; }
    if (t == 1023) off[N] = ls[1023];
}

__global__ __launch_bounds__(256) void scatter2_kernel(
    const int* __restrict__ src, const int* __restrict__ dst,
    int* __restrict__ cursor, int* __restrict__ src_s,
    int* __restrict__ eid_s, int E)
{
    for (int e = blockIdx.x * blockDim.x + threadIdx.x; e < E;
         e += gridDim.x * blockDim.x) {
        const int pos = atomicAdd(&cursor[dst[e]], 1);
        src_s[pos] = src[e];
        eid_s[pos] = e;
    }
}

// ---------------------------------------------------------------------------
// Streaming f32 -> bf16 converts (coalesced both sides)
// ---------------------------------------------------------------------------
__global__ __launch_bounds__(256) void conv_ea(
    const float* __restrict__ ea, unsigned short* __restrict__ ea_b,
    long long total4)
{
    for (long long i = blockIdx.x * 256LL + threadIdx.x; i < total4;
         i += gridDim.x * 256LL) {
        const float4 v = reinterpret_cast<const float4*>(ea)[i];
        ushort4 o;
        o.x = __builtin_bit_cast(unsigned short, (__bf16)v.x);
        o.y = __builtin_bit_cast(unsigned short, (__bf16)v.y);
        o.z = __builtin_bit_cast(unsigned short, (__bf16)v.z);
        o.w = __builtin_bit_cast(unsigned short, (__bf16)v.w);
        reinterpret_cast<ushort4*>(ea_b)[i] = o;
    }
}

__global__ __launch_bounds__(256) void conv_s(
    const float* __restrict__ s0, unsigned int* __restrict__ sb,
    long long total4)
{
    for (long long i = blockIdx.x * 256LL + threadIdx.x; i < total4;
         i += gridDim.x * 256LL) {
        const float4 v = reinterpret_cast<const float4*>(s0)[i];
        const unsigned a =
            (unsigned)__builtin_bit_cast(unsigned short, (__bf16)v.x) |
            ((unsigned)__builtin_bit_cast(unsigned short, (__bf16)v.y) << 16);
        const unsigned b =
            (unsigned)__builtin_bit_cast(unsigned short, (__bf16)v.z) |
            ((unsigned)__builtin_bit_cast(unsigned short, (__bf16)v.w) << 16);
        reinterpret_cast<uint2*>(sb)[i] = make_uint2(a, b);
    }
}

// ---------------------------------------------------------------------------
// We -> bf16 B-fragments for mfma_f32_16x16x32_bf16.
// ---------------------------------------------------------------------------
__global__ void prep_we(const float* __restrict__ We, bf16x8* __restrict__ WeB)
{
    const int t = blockIdx.x * blockDim.x + threadIdx.x;
    if (t >= NLAYER * 16 * 64) return;
    const int lane  = t & 63;
    const int frag  = (t >> 6) & 15;
    const int layer = t >> 10;
    const int kt = frag >> 3, ct = frag & 7;
    const int col = ct * 16 + (lane & 15);
    const int k0  = kt * 32 + (lane >> 4) * 8;
    bf16x8 v;
    #pragma unroll
    for (int j = 0; j < 8; ++j)
        v[j] = (__bf16)We[(long long)layer * EDD * HH + (k0 + j) * HH + col];
    WeB[t] = v;
}

// ---------------------------------------------------------------------------
// MFMA aggregation: block per node (grid-stride), 4 waves split 8 col-tiles.
// Neighbor features gathered from the bf16 shadow copy sb (half the bytes of
// f32 s); self term + output stay f32.
// ---------------------------------------------------------------------------
__global__ __launch_bounds__(256) void gine_agg_mfma(
    const float* __restrict__ s,              // f32 state (self term)
    const unsigned short* __restrict__ sb,    // bf16 shadow of s (gathers)
    const int* __restrict__ src_s,            // dst-sorted src ids, padded
    const int* __restrict__ eid_s,            // dst-sorted edge ids, padded
    const int* __restrict__ off,              // [N+1]
    const unsigned short* __restrict__ ea_b,  // [E][64] bf16, original order
    const bf16x8* __restrict__ WeB,           // this layer's 16 frags
    const float* __restrict__ be,
    float* __restrict__ hbuf,                 // out: s + agg
    int N)
{
    const int wave = threadIdx.x >> 6;   // col-tiles {2*wave, 2*wave+1}
    const int lane = threadIdx.x & 63;
    const int lmod = lane & 15;
    const int ldiv = lane >> 4;

    const bf16x8 wb00 = WeB[(0 * 8 + 2 * wave    ) * 64 + lane];
    const bf16x8 wb01 = WeB[(0 * 8 + 2 * wave + 1) * 64 + lane];
    const bf16x8 wb10 = WeB[(1 * 8 + 2 * wave    ) * 64 + lane];
    const bf16x8 wb11 = WeB[(1 * 8 + 2 * wave + 1) * 64 + lane];

    const int col0 = (2 * wave)     * 16 + lmod;
    const int col1 = (2 * wave + 1) * 16 + lmod;
    const float bev0 = be[col0];
    const float bev1 = be[col1];

    for (int n = blockIdx.x; n < N; n += gridDim.x) {
        const int p0 = off[n], p1 = off[n + 1];
        float acc0 = 0.f, acc1 = 0.f;

        for (int p = p0; p < p1; p += 16) {
            const int rem = p1 - p;
            const int rowid = eid_s[p + lmod];
            const unsigned short* arow =
                ea_b + (long long)rowid * EDD + ldiv * 8;
            const bf16x8 a0 = *reinterpret_cast<const bf16x8*>(arow);
            const bf16x8 a1 = *reinterpret_cast<const bf16x8*>(arow + 32);

            const int ms0 = src_s[p + ldiv * 4 + 0];
            const int ms1 = src_s[p + ldiv * 4 + 1];
            const int ms2 = src_s[p + ldiv * 4 + 2];
            const int ms3 = src_s[p + ldiv * 4 + 3];

            f32x4 c0 = {0.f, 0.f, 0.f, 0.f};
            f32x4 c1 = {0.f, 0.f, 0.f, 0.f};
            c0 = __builtin_amdgcn_mfma_f32_16x16x32_bf16(a0, wb00, c0, 0, 0, 0);
            c0 = __builtin_amdgcn_mfma_f32_16x16x32_bf16(a1, wb10, c0, 0, 0, 0);
            c1 = __builtin_amdgcn_mfma_f32_16x16x32_bf16(a0, wb01, c1, 0, 0, 0);
            c1 = __builtin_amdgcn_mfma_f32_16x16x32_bf16(a1, wb11, c1, 0, 0, 0);

            const int base_row = ldiv * 4;
            const int msv[4] = {ms0, ms1, ms2, ms3};
            #pragma unroll
            for (int r = 0; r < 4; ++r) {
                if (base_row + r < rem) {
                    const long long srow = (long long)msv[r] * HH;
                    const float sv0 = __uint_as_float(
                        (unsigned)sb[srow + col0] << 16);
                    const float sv1 = __uint_as_float(
                        (unsigned)sb[srow + col1] << 16);
                    acc0 += fmaxf(sv0 + c0[r] + bev0, 0.f);
                    acc1 += fmaxf(sv1 + c1[r] + bev1, 0.f);
                }
            }
        }

        acc0 += __shfl_xor(acc0, 16, 64);
        acc0 += __shfl_xor(acc0, 32, 64);
        acc1 += __shfl_xor(acc1, 16, 64);
        acc1 += __shfl_xor(acc1, 32, 64);

        if (ldiv < 2) {
            const int col = (ldiv == 0) ? col0 : col1;
            const float a = (ldiv == 0) ? acc0 : acc1;
            hbuf[(long long)n * HH + col] = s[(long long)n * HH + col] + a;
        }
    }
}

// ---------------------------------------------------------------------------
// Fused node MLP: t1 = silu(h@W1+b1); v = s + t1@W2 + b2;
// s_out = silu(LN(v)*gamma+beta); also writes bf16 shadow sb_out.
// Both weights in LDS (128 KB), 1024-thread blocks (16 waves, 1 block/CU).
// ---------------------------------------------------------------------------
__global__ __launch_bounds__(1024) void gine_mlp(
    const float* __restrict__ s_in,
    const float* __restrict__ h,     // from agg (may alias s_out)
    const float* __restrict__ W1, const float* __restrict__ b1,
    const float* __restrict__ W2, const float* __restrict__ b2,
    const float* __restrict__ gamma, const float* __restrict__ beta,
    float* __restrict__ s_out,
    unsigned int* __restrict__ sb_out,   // packed 2xbf16 per uint, [N*64]
    int N)
{
    __shared__ float sW1[HH * HH];   // 64 KB
    __shared__ float sW2[HH * HH];   // 64 KB
    for (int i = threadIdx.x; i < HH * HH / 4; i += 1024) {
        reinterpret_cast<float4*>(sW1)[i] = reinterpret_cast<const float4*>(W1)[i];
        reinterpret_cast<float4*>(sW2)[i] = reinterpret_cast<const float4*>(W2)[i];
    }
    __syncthreads();

    const int wave = threadIdx.x >> 6;   // 0..15
    const int lane = threadIdx.x & 63;
    const int c0 = 2 * lane;
    const float b1x = b1[c0], b1y = b1[c0 + 1];
    const float b2x = b2[c0], b2y = b2[c0 + 1];
    const float gx = gamma[c0], gy = gamma[c0 + 1];
    const float ex = beta[c0],  ey = beta[c0 + 1];

    for (int n = blockIdx.x * 16 + wave; n < N; n += gridDim.x * 16) {
        const float2 hv = *reinterpret_cast<const float2*>(&h[(long long)n * HH + c0]);

        float tx = b1x, ty = b1y;
        #pragma unroll
        for (int m = 0; m < 64; ++m) {
            const float h0 = __uint_as_float(__builtin_amdgcn_readlane(__float_as_uint(hv.x), m));
            const float h1 = __uint_as_float(__builtin_amdgcn_readlane(__float_as_uint(hv.y), m));
            const float2 w0 = *reinterpret_cast<const float2*>(&sW1[(2 * m) * HH + c0]);
            const float2 w1 = *reinterpret_cast<const float2*>(&sW1[(2 * m + 1) * HH + c0]);
            tx = fmaf(h0, w0.x, tx); ty = fmaf(h0, w0.y, ty);
            tx = fmaf(h1, w1.x, tx); ty = fmaf(h1, w1.y, ty);
        }
        tx = tx / (1.f + __expf(-tx));
        ty = ty / (1.f + __expf(-ty));
        const float2 tv = make_float2(tx, ty);

        float accx = b2x, accy = b2y;
        #pragma unroll
        for (int m = 0; m < 64; ++m) {
            const float t0 = __uint_as_float(__builtin_amdgcn_readlane(__float_as_uint(tv.x), m));
            const float t1 = __uint_as_float(__builtin_amdgcn_readlane(__float_as_uint(tv.y), m));
            const float2 w0 = *reinterpret_cast<const float2*>(&sW2[(2 * m) * HH + c0]);
            const float2 w1 = *reinterpret_cast<const float2*>(&sW2[(2 * m + 1) * HH + c0]);
            accx = fmaf(t0, w0.x, accx); accy = fmaf(t0, w0.y, accy);
            accx = fmaf(t1, w1.x, accx); accy = fmaf(t1, w1.y, accy);
        }

        const float2 sv = *reinterpret_cast<const float2*>(&s_in[(long long)n * HH + c0]);
        const float vx = sv.x + accx;
        const float vy = sv.y + accy;

        float sum = vx + vy;
        float ssq = vx * vx + vy * vy;
        #pragma unroll
        for (int o = 32; o > 0; o >>= 1) {
            sum += __shfl_xor(sum, o, 64);
            ssq += __shfl_xor(ssq, o, 64);
        }
        const float mu = sum * (1.0f / HH);
        const float var = ssq * (1.0f / HH) - mu * mu;
        const float rs = rsqrtf(var + LN_EPS);

        float ox = (vx - mu) * rs * gx + ex;
        float oy = (vy - mu) * rs * gy + ey;
        ox = ox / (1.f + __expf(-ox));
        oy = oy / (1.f + __expf(-oy));

        *reinterpret_cast<float2*>(&s_out[(long long)n * HH + c0]) = make_float2(ox, oy);
        const unsigned lo = __builtin_bit_cast(unsigned short, (__bf16)ox);
        const unsigned hi = __builtin_bit_cast(unsigned short, (__bf16)oy);
        sb_out[(long long)n * 64 + lane] = lo | (hi << 16);
    }
}

// ---------------------------------------------------------------------------
extern "C" void kernel_launch(void* const* d_in, const int* in_sizes, int n_in,
                              void* d_out, int out_size, void* d_ws, size_t ws_size,
                              hipStream_t stream) {
    const float* s0  = (const float*)d_in[0];
    const int*   ei  = (const int*)  d_in[1];
    const float* ea  = (const float*)d_in[2];
    const float* We  = (const float*)d_in[3];
    const float* be  = (const float*)d_in[4];
    const float* W1  = (const float*)d_in[5];
    const float* b1  = (const float*)d_in[6];
    const float* W2  = (const float*)d_in[7];
    const float* b2  = (const float*)d_in[8];
    const float* gm  = (const float*)d_in[9];
    const float* bt  = (const float*)d_in[10];

    const int NH = in_sizes[0];          // N * 128
    const int N  = NH / HH;
    const int E  = in_sizes[1] / 2;
    const int* src = ei;
    const int* dst = ei + E;

    // ws layout; hbuf aliases d_out (safe: mlp reads its h row before writing)
    float*          sbuf  = (float*)d_ws;                       // [N*H] f32
    unsigned short* sb    = (unsigned short*)(sbuf + NH);       // [N*H] bf16 shadow
    unsigned short* ea_b  = sb + NH;                            // [E*64] bf16
    bf16x8*         WeB   = (bf16x8*)(ea_b + (size_t)E * EDD);  // [3*16*64]
    int*            src_s = (int*)(WeB + NLAYER * 16 * 64);     // [E+16]
    int*            eid_s = src_s + (E + 16);                   // [E+16]
    int*            off   = eid_s + (E + 16);                   // [N+1]
    int*            cursor= off + (N + 1);                      // [N] (also cnt)
    float*          hbuf  = (float*)d_out;                      // [N*H] f32

    hipMemcpyAsync(sbuf, s0, sizeof(float) * NH, hipMemcpyDeviceToDevice, stream);

    // ---- one-time preprocessing
    hipMemsetAsync(cursor, 0, sizeof(int) * N, stream);
    hist_kernel<<<1024, 256, 0, stream>>>(dst, cursor, E);
    scan_kernel<<<1, 1024, 0, stream>>>(cursor, off, N);
    hipMemcpyAsync(cursor, off, sizeof(int) * N, hipMemcpyDeviceToDevice, stream);
    scatter2_kernel<<<1024, 256, 0, stream>>>(src, dst, cursor, src_s, eid_s, E);
    hipMemsetAsync(src_s + E, 0, 16 * sizeof(int), stream);
    hipMemsetAsync(eid_s + E, 0, 16 * sizeof(int), stream);
    conv_ea<<<2048, 256, 0, stream>>>(ea, ea_b, (long long)E * EDD / 4);
    conv_s<<<1024, 256, 0, stream>>>(s0, (unsigned int*)sb, (long long)NH / 4);
    prep_we<<<12, 256, 0, stream>>>(We, WeB);

    for (int l = 0; l < NLAYER; ++l) {
        gine_agg_mfma<<<4096, 256, 0, stream>>>(sbuf, sb, src_s, eid_s, off, ea_b,
                                                WeB + (size_t)l * 16 * 64,
                                                be + l * HH, hbuf, N);
        float* sout = (l == NLAYER - 1) ? (float*)d_out : sbuf;
        gine_mlp<<<256, 1024, 0, stream>>>(sbuf, hbuf,
                                           W1 + (long long)l * HH * HH, b1 + l * HH,
                                           W2 + (long long)l * HH * HH, b2 + l * HH,
                                           gm + l * HH, bt + l * HH,
                                           sout, (unsigned int*)sb, N);
    }
}

// Round 8
// 1233.062 us; speedup vs baseline: 2.4160x; 2.4160x over previous
//
#include <hip/hip_runtime.h>
#include <hip/hip_bf16.h>

#define HH 128   // hidden
#define EDD 64   // edge_dim
#define NLAYER 3
#define LN_EPS 1e-5f

typedef __attribute__((ext_vector_type(8))) __bf16 bf16x8;
typedef __attribute__((ext_vector_type(4))) float f32x4;

static __device__ __forceinline__ float bf2f(unsigned short u) {
    return __uint_as_float(((unsigned)u) << 16);
}
static __device__ __forceinline__ unsigned short f2bf(float f) {
    return __builtin_bit_cast(unsigned short, (__bf16)f);
}
static __device__ __forceinline__ float silu(float x) {
    return x / (1.f + __expf(-x));
}

// ---------------------------------------------------------------------------
// CSR build (once per call; edge_index is layer-invariant)
// ---------------------------------------------------------------------------
__global__ __launch_bounds__(256) void hist_kernel(
    const int* __restrict__ dst, int* __restrict__ cnt, int E)
{
    for (int e = blockIdx.x * blockDim.x + threadIdx.x; e < E;
         e += gridDim.x * blockDim.x)
        atomicAdd(&cnt[dst[e]], 1);
}

__global__ __launch_bounds__(1024) void scan_kernel(
    const int* __restrict__ cnt, int* __restrict__ off, int N)
{
    __shared__ int ls[1024];
    const int t = threadIdx.x;
    const int C = (N + 1023) >> 10;
    const int lo = t * C;
    const int hi = min(lo + C, N);
    int sum = 0;
    for (int i = lo; i < hi; ++i) sum += cnt[i];
    ls[t] = sum;
    __syncthreads();
    for (int d = 1; d < 1024; d <<= 1) {
        int v = (t >= d) ? ls[t - d] : 0;
        __syncthreads();
        ls[t] += v;
        __syncthreads();
    }
    int excl = (t == 0) ? 0 : ls[t - 1];
    for (int i = lo; i < hi; ++i) { off[i] = excl; excl += cnt[i]; }
    if (t == 1023) off[N] = ls[1023];
}

__global__ __launch_bounds__(256) void scatter2_kernel(
    const int* __restrict__ src, const int* __restrict__ dst,
    int* __restrict__ cursor, int* __restrict__ src_s,
    int* __restrict__ eid_s, int E)
{
    for (int e = blockIdx.x * blockDim.x + threadIdx.x; e < E;
         e += gridDim.x * blockDim.x) {
        const int pos = atomicAdd(&cursor[dst[e]], 1);
        src_s[pos] = src[e];
        eid_s[pos] = e;
    }
}

// ---------------------------------------------------------------------------
// Streaming f32 -> bf16 converts (coalesced both sides)
// ---------------------------------------------------------------------------
__global__ __launch_bounds__(256) void conv_ea(
    const float* __restrict__ ea, unsigned short* __restrict__ ea_b,
    long long total4)
{
    for (long long i = blockIdx.x * 256LL + threadIdx.x; i < total4;
         i += gridDim.x * 256LL) {
        const float4 v = reinterpret_cast<const float4*>(ea)[i];
        ushort4 o;
        o.x = f2bf(v.x); o.y = f2bf(v.y); o.z = f2bf(v.z); o.w = f2bf(v.w);
        reinterpret_cast<ushort4*>(ea_b)[i] = o;
    }
}

__global__ __launch_bounds__(256) void conv_s(
    const float* __restrict__ s0, unsigned int* __restrict__ sbp,
    long long total4)
{
    for (long long i = blockIdx.x * 256LL + threadIdx.x; i < total4;
         i += gridDim.x * 256LL) {
        const float4 v = reinterpret_cast<const float4*>(s0)[i];
        const unsigned a = (unsigned)f2bf(v.x) | ((unsigned)f2bf(v.y) << 16);
        const unsigned b = (unsigned)f2bf(v.z) | ((unsigned)f2bf(v.w) << 16);
        reinterpret_cast<uint2*>(sbp)[i] = make_uint2(a, b);
    }
}

// ---------------------------------------------------------------------------
// We (64x128) -> bf16 B-fragments: frag (kt,ct), lane l holds
// B[k = kt*32 + (l>>4)*8 + j][col = ct*16 + (l&15)], kt<2, ct<8.
// ---------------------------------------------------------------------------
__global__ void prep_we(const float* __restrict__ We, bf16x8* __restrict__ WeB)
{
    const int t = blockIdx.x * blockDim.x + threadIdx.x;
    if (t >= NLAYER * 16 * 64) return;
    const int lane  = t & 63;
    const int frag  = (t >> 6) & 15;
    const int layer = t >> 10;
    const int kt = frag >> 3, ct = frag & 7;
    const int col = ct * 16 + (lane & 15);
    const int k0  = kt * 32 + (lane >> 4) * 8;
    bf16x8 v;
    #pragma unroll
    for (int j = 0; j < 8; ++j)
        v[j] = (__bf16)We[(long long)layer * EDD * HH + (k0 + j) * HH + col];
    WeB[t] = v;
}

// ---------------------------------------------------------------------------
// W (128x128) -> bf16 A^T fragments: frag (kt,ct), kt<4, ct<8; lane l holds
// W[k = kt*32 + (l>>4)*8 + j][outcol = ct*16 + (l&15)].
// Used as the A operand of D = W^T . x^T (rows of D = out channels).
// ---------------------------------------------------------------------------
__global__ void prep_w128(const float* __restrict__ W, bf16x8* __restrict__ WB)
{
    const int t = blockIdx.x * blockDim.x + threadIdx.x;
    if (t >= NLAYER * 32 * 64) return;
    const int lane  = t & 63;
    const int frag  = (t >> 6) & 31;
    const int layer = t >> 11;
    const int kt = frag >> 3, ct = frag & 7;
    const int col = ct * 16 + (lane & 15);
    const int k0  = kt * 32 + (lane >> 4) * 8;
    bf16x8 v;
    #pragma unroll
    for (int j = 0; j < 8; ++j)
        v[j] = (__bf16)W[(long long)layer * HH * HH + (k0 + j) * HH + col];
    WB[t] = v;
}

// ---------------------------------------------------------------------------
// MFMA aggregation: ONE WAVE PER NODE (grid-stride). All 16 We frags live in
// 64 VGPRs; per 16-edge chunk: 2 A-loads (eid-indirect), 16 MFMA (8 col-tiles),
// masked relu-sum with bf16 neighbor gathers. h = s + agg written once.
// ---------------------------------------------------------------------------
__global__ __launch_bounds__(256) void gine_agg_mfma(
    const float* __restrict__ s,              // f32 state (self term)
    const unsigned short* __restrict__ sb,    // bf16 shadow of s (gathers)
    const int* __restrict__ src_s,            // dst-sorted src ids, padded
    const int* __restrict__ eid_s,            // dst-sorted edge ids, padded
    const int* __restrict__ off,              // [N+1]
    const unsigned short* __restrict__ ea_b,  // [E][64] bf16, original order
    const bf16x8* __restrict__ WeB,           // this layer's 16 frags
    const float* __restrict__ be,
    float* __restrict__ hbuf,                 // out: s + agg
    int N)
{
    const int lane = threadIdx.x & 63;
    const int lmod = lane & 15;
    const int ldiv = lane >> 4;

    bf16x8 wf[2][8];
    #pragma unroll
    for (int kt = 0; kt < 2; ++kt)
        #pragma unroll
        for (int ct = 0; ct < 8; ++ct)
            wf[kt][ct] = WeB[(kt * 8 + ct) * 64 + lane];

    float bev[8];
    #pragma unroll
    for (int ct = 0; ct < 8; ++ct) bev[ct] = be[ct * 16 + lmod];

    const int wid = blockIdx.x * 4 + (threadIdx.x >> 6);
    const int nwaves = gridDim.x * 4;

    for (int n = wid; n < N; n += nwaves) {
        const int p0 = off[n], p1 = off[n + 1];
        float acc[8];
        #pragma unroll
        for (int ct = 0; ct < 8; ++ct) acc[ct] = 0.f;

        for (int p = p0; p < p1; p += 16) {
            const int rem = p1 - p;
            const int rowid = eid_s[p + lmod];
            const unsigned short* arow = ea_b + (long long)rowid * EDD + ldiv * 8;
            const bf16x8 a0 = *reinterpret_cast<const bf16x8*>(arow);
            const bf16x8 a1 = *reinterpret_cast<const bf16x8*>(arow + 32);

            int msv[4];
            #pragma unroll
            for (int r = 0; r < 4; ++r) msv[r] = src_s[p + ldiv * 4 + r];

            #pragma unroll
            for (int ct = 0; ct < 8; ++ct) {
                f32x4 c = {0.f, 0.f, 0.f, 0.f};
                c = __builtin_amdgcn_mfma_f32_16x16x32_bf16(a0, wf[0][ct], c, 0, 0, 0);
                c = __builtin_amdgcn_mfma_f32_16x16x32_bf16(a1, wf[1][ct], c, 0, 0, 0);
                #pragma unroll
                for (int r = 0; r < 4; ++r) {
                    if (ldiv * 4 + r < rem) {
                        const float sv = bf2f(sb[(long long)msv[r] * HH + ct * 16 + lmod]);
                        acc[ct] += fmaxf(sv + c[r] + bev[ct], 0.f);
                    }
                }
            }
        }

        #pragma unroll
        for (int ct = 0; ct < 8; ++ct) {
            acc[ct] += __shfl_xor(acc[ct], 16, 64);
            acc[ct] += __shfl_xor(acc[ct], 32, 64);
        }
        if (ldiv == 0) {
            const long long nb = (long long)n * HH;
            #pragma unroll
            for (int ct = 0; ct < 8; ++ct) {
                const int c0 = ct * 16 + lmod;
                hbuf[nb + c0] = s[nb + c0] + acc[ct];
            }
        }
    }
}

// ---------------------------------------------------------------------------
// MLP stage 1 (MFMA): t1 = silu(h @ W1 + b1)  as  D = W1^T . h^T.
// Block = 4 waves sharing a 16-node tile; wave owns col-tiles {2w,2w+1}.
// Lane: node = tile*16 + (lane&15); D rows = out channels.
// ---------------------------------------------------------------------------
__global__ __launch_bounds__(256) void gine_mlp1(
    const float* __restrict__ h,       // [N][128] f32
    const bf16x8* __restrict__ W1B,    // this layer's 32 frags
    const float* __restrict__ b1,
    unsigned short* __restrict__ t1,   // [N][128] bf16 out
    int N)
{
    const int wave = threadIdx.x >> 6;
    const int lane = threadIdx.x & 63;
    const int lmod = lane & 15;
    const int ldiv = lane >> 4;

    bf16x8 wf[4][2];
    #pragma unroll
    for (int kt = 0; kt < 4; ++kt) {
        wf[kt][0] = W1B[(kt * 8 + 2 * wave    ) * 64 + lane];
        wf[kt][1] = W1B[(kt * 8 + 2 * wave + 1) * 64 + lane];
    }
    float4 bv[2];
    bv[0] = *reinterpret_cast<const float4*>(&b1[(2 * wave)     * 16 + ldiv * 4]);
    bv[1] = *reinterpret_cast<const float4*>(&b1[(2 * wave + 1) * 16 + ldiv * 4]);

    const int ntiles = (N + 15) >> 4;
    for (int t = blockIdx.x; t < ntiles; t += gridDim.x) {
        const int node = t * 16 + lmod;
        const long long hb = (long long)min(node, N - 1) * HH;

        f32x4 c0 = {0.f, 0.f, 0.f, 0.f};
        f32x4 c1 = {0.f, 0.f, 0.f, 0.f};
        #pragma unroll
        for (int kt = 0; kt < 4; ++kt) {
            const float4 f0 = *reinterpret_cast<const float4*>(&h[hb + kt * 32 + ldiv * 8]);
            const float4 f1 = *reinterpret_cast<const float4*>(&h[hb + kt * 32 + ldiv * 8 + 4]);
            bf16x8 hf;
            hf[0] = (__bf16)f0.x; hf[1] = (__bf16)f0.y;
            hf[2] = (__bf16)f0.z; hf[3] = (__bf16)f0.w;
            hf[4] = (__bf16)f1.x; hf[5] = (__bf16)f1.y;
            hf[6] = (__bf16)f1.z; hf[7] = (__bf16)f1.w;
            c0 = __builtin_amdgcn_mfma_f32_16x16x32_bf16(wf[kt][0], hf, c0, 0, 0, 0);
            c1 = __builtin_amdgcn_mfma_f32_16x16x32_bf16(wf[kt][1], hf, c1, 0, 0, 0);
        }

        if (node < N) {
            const long long tb = (long long)node * HH;
            #pragma unroll
            for (int ctl = 0; ctl < 2; ++ctl) {
                const f32x4 cc = ctl ? c1 : c0;
                const int oc0 = (2 * wave + ctl) * 16 + ldiv * 4;
                const float v0 = silu(cc[0] + (ctl ? bv[1].x : bv[0].x));
                const float v1 = silu(cc[1] + (ctl ? bv[1].y : bv[0].y));
                const float v2 = silu(cc[2] + (ctl ? bv[1].z : bv[0].z));
                const float v3 = silu(cc[3] + (ctl ? bv[1].w : bv[0].w));
                uint2 pk;
                pk.x = (unsigned)f2bf(v0) | ((unsigned)f2bf(v1) << 16);
                pk.y = (unsigned)f2bf(v2) | ((unsigned)f2bf(v3) << 16);
                *reinterpret_cast<uint2*>(&t1[tb + oc0]) = pk;
            }
        }
    }
}

// ---------------------------------------------------------------------------
// MLP stage 2 (MFMA) + residual + LayerNorm + SiLU + bf16 shadow:
//   v = s + t1 @ W2 + b2 ; s_out = silu(LN(v)*gamma+beta)
// Same transposed layout; LN via wave shfl + tiny cross-wave LDS exchange.
// ---------------------------------------------------------------------------
__global__ __launch_bounds__(256) void gine_mlp2(
    const float* __restrict__ s_in,
    const unsigned short* __restrict__ t1,   // [N][128] bf16
    const bf16x8* __restrict__ W2B,
    const float* __restrict__ b2,
    const float* __restrict__ gamma,
    const float* __restrict__ beta,
    float* __restrict__ s_out,
    unsigned short* __restrict__ sb_out,     // bf16 shadow
    int N)
{
    __shared__ float2 red[4][16];

    const int wave = threadIdx.x >> 6;
    const int lane = threadIdx.x & 63;
    const int lmod = lane & 15;
    const int ldiv = lane >> 4;

    bf16x8 wf[4][2];
    #pragma unroll
    for (int kt = 0; kt < 4; ++kt) {
        wf[kt][0] = W2B[(kt * 8 + 2 * wave    ) * 64 + lane];
        wf[kt][1] = W2B[(kt * 8 + 2 * wave + 1) * 64 + lane];
    }
    float4 bv[2], gv[2], ev[2];
    #pragma unroll
    for (int ctl = 0; ctl < 2; ++ctl) {
        const int oc0 = (2 * wave + ctl) * 16 + ldiv * 4;
        bv[ctl] = *reinterpret_cast<const float4*>(&b2[oc0]);
        gv[ctl] = *reinterpret_cast<const float4*>(&gamma[oc0]);
        ev[ctl] = *reinterpret_cast<const float4*>(&beta[oc0]);
    }

    const int ntiles = (N + 15) >> 4;
    for (int t = blockIdx.x; t < ntiles; t += gridDim.x) {
        const int node = t * 16 + lmod;
        const long long nb = (long long)min(node, N - 1) * HH;

        f32x4 c0 = {0.f, 0.f, 0.f, 0.f};
        f32x4 c1 = {0.f, 0.f, 0.f, 0.f};
        #pragma unroll
        for (int kt = 0; kt < 4; ++kt) {
            const bf16x8 tf = *reinterpret_cast<const bf16x8*>(
                &t1[nb + kt * 32 + ldiv * 8]);
            c0 = __builtin_amdgcn_mfma_f32_16x16x32_bf16(wf[kt][0], tf, c0, 0, 0, 0);
            c1 = __builtin_amdgcn_mfma_f32_16x16x32_bf16(wf[kt][1], tf, c1, 0, 0, 0);
        }

        float v[2][4];
        float sum = 0.f, ssq = 0.f;
        #pragma unroll
        for (int ctl = 0; ctl < 2; ++ctl) {
            const int oc0 = (2 * wave + ctl) * 16 + ldiv * 4;
            const float4 sv = *reinterpret_cast<const float4*>(&s_in[nb + oc0]);
            const f32x4 cc = ctl ? c1 : c0;
            v[ctl][0] = sv.x + cc[0] + bv[ctl].x;
            v[ctl][1] = sv.y + cc[1] + bv[ctl].y;
            v[ctl][2] = sv.z + cc[2] + bv[ctl].z;
            v[ctl][3] = sv.w + cc[3] + bv[ctl].w;
            #pragma unroll
            for (int r = 0; r < 4; ++r) { sum += v[ctl][r]; ssq += v[ctl][r] * v[ctl][r]; }
        }
        sum += __shfl_xor(sum, 16, 64); sum += __shfl_xor(sum, 32, 64);
        ssq += __shfl_xor(ssq, 16, 64); ssq += __shfl_xor(ssq, 32, 64);
        if (ldiv == 0) red[wave][lmod] = make_float2(sum, ssq);
        __syncthreads();
        float ts = 0.f, tq = 0.f;
        #pragma unroll
        for (int w = 0; w < 4; ++w) {
            const float2 rr = red[w][lmod];
            ts += rr.x; tq += rr.y;
        }
        __syncthreads();

        const float mu = ts * (1.0f / HH);
        const float var = tq * (1.0f / HH) - mu * mu;
        const float rs = rsqrtf(var + LN_EPS);

        if (node < N) {
            #pragma unroll
            for (int ctl = 0; ctl < 2; ++ctl) {
                const int oc0 = (2 * wave + ctl) * 16 + ldiv * 4;
                float o[4];
                o[0] = silu((v[ctl][0] - mu) * rs * gv[ctl].x + ev[ctl].x);
                o[1] = silu((v[ctl][1] - mu) * rs * gv[ctl].y + ev[ctl].y);
                o[2] = silu((v[ctl][2] - mu) * rs * gv[ctl].z + ev[ctl].z);
                o[3] = silu((v[ctl][3] - mu) * rs * gv[ctl].w + ev[ctl].w);
                *reinterpret_cast<float4*>(&s_out[nb + oc0]) =
                    make_float4(o[0], o[1], o[2], o[3]);
                uint2 pk;
                pk.x = (unsigned)f2bf(o[0]) | ((unsigned)f2bf(o[1]) << 16);
                pk.y = (unsigned)f2bf(o[2]) | ((unsigned)f2bf(o[3]) << 16);
                *reinterpret_cast<uint2*>(&sb_out[nb + oc0]) = pk;
            }
        }
    }
}

// ---------------------------------------------------------------------------
extern "C" void kernel_launch(void* const* d_in, const int* in_sizes, int n_in,
                              void* d_out, int out_size, void* d_ws, size_t ws_size,
                              hipStream_t stream) {
    const float* s0  = (const float*)d_in[0];
    const int*   ei  = (const int*)  d_in[1];
    const float* ea  = (const float*)d_in[2];
    const float* We  = (const float*)d_in[3];
    const float* be  = (const float*)d_in[4];
    const float* W1  = (const float*)d_in[5];
    const float* b1  = (const float*)d_in[6];
    const float* W2  = (const float*)d_in[7];
    const float* b2  = (const float*)d_in[8];
    const float* gm  = (const float*)d_in[9];
    const float* bt  = (const float*)d_in[10];

    const int NH = in_sizes[0];          // N * 128
    const int N  = NH / HH;
    const int E  = in_sizes[1] / 2;
    const int* src = ei;
    const int* dst = ei + E;

    // ws layout; hbuf aliases d_out (mlp1 consumes h before mlp2 writes d_out)
    float*          sbuf  = (float*)d_ws;                       // [N*H] f32
    unsigned short* sb    = (unsigned short*)(sbuf + NH);       // [N*H] bf16 shadow
    unsigned short* t1b   = sb + NH;                            // [N*H] bf16 t1
    unsigned short* ea_b  = t1b + NH;                           // [E*64] bf16
    bf16x8*         WeB   = (bf16x8*)(ea_b + (size_t)E * EDD);  // [3*16*64]
    bf16x8*         W1B   = WeB + NLAYER * 16 * 64;             // [3*32*64]
    bf16x8*         W2B   = W1B + NLAYER * 32 * 64;             // [3*32*64]
    int*            src_s = (int*)(W2B + NLAYER * 32 * 64);     // [E+16]
    int*            eid_s = src_s + (E + 16);                   // [E+16]
    int*            off   = eid_s + (E + 16);                   // [N+1]
    int*            cursor= off + (N + 1);                      // [N] (also cnt)
    float*          hbuf  = (float*)d_out;                      // [N*H] f32

    hipMemcpyAsync(sbuf, s0, sizeof(float) * NH, hipMemcpyDeviceToDevice, stream);

    // ---- one-time preprocessing
    hipMemsetAsync(cursor, 0, sizeof(int) * N, stream);
    hist_kernel<<<1024, 256, 0, stream>>>(dst, cursor, E);
    scan_kernel<<<1, 1024, 0, stream>>>(cursor, off, N);
    hipMemcpyAsync(cursor, off, sizeof(int) * N, hipMemcpyDeviceToDevice, stream);
    scatter2_kernel<<<1024, 256, 0, stream>>>(src, dst, cursor, src_s, eid_s, E);
    hipMemsetAsync(src_s + E, 0, 16 * sizeof(int), stream);
    hipMemsetAsync(eid_s + E, 0, 16 * sizeof(int), stream);
    conv_ea<<<2048, 256, 0, stream>>>(ea, ea_b, (long long)E * EDD / 4);
    conv_s<<<1024, 256, 0, stream>>>(s0, (unsigned int*)sb, (long long)NH / 4);
    prep_we<<<12, 256, 0, stream>>>(We, WeB);
    prep_w128<<<24, 256, 0, stream>>>(W1, W1B);
    prep_w128<<<24, 256, 0, stream>>>(W2, W2B);

    for (int l = 0; l < NLAYER; ++l) {
        gine_agg_mfma<<<4096, 256, 0, stream>>>(sbuf, sb, src_s, eid_s, off, ea_b,
                                                WeB + (size_t)l * 16 * 64,
                                                be + l * HH, hbuf, N);
        gine_mlp1<<<1024, 256, 0, stream>>>(hbuf,
                                            W1B + (size_t)l * 32 * 64,
                                            b1 + l * HH, t1b, N);
        float* sout = (l == NLAYER - 1) ? (float*)d_out : sbuf;
        gine_mlp2<<<1024, 256, 0, stream>>>(sbuf, t1b,
                                            W2B + (size_t)l * 32 * 64,
                                            b2 + l * HH,
                                            gm + l * HH, bt + l * HH,
                                            sout, sb, N);
    }
}

// Round 9
// 889.689 us; speedup vs baseline: 3.3485x; 1.3859x over previous
//
#include <hip/hip_runtime.h>
#include <hip/hip_bf16.h>

#define HH 128   // hidden
#define EDD 64   // edge_dim
#define NLAYER 3
#define LN_EPS 1e-5f

typedef __attribute__((ext_vector_type(8))) __bf16 bf16x8;
typedef __attribute__((ext_vector_type(4))) float f32x4;

static __device__ __forceinline__ float bf2f(unsigned short u) {
    return __uint_as_float(((unsigned)u) << 16);
}
static __device__ __forceinline__ unsigned short f2bf(float f) {
    return __builtin_bit_cast(unsigned short, (__bf16)f);
}
static __device__ __forceinline__ float silu(float x) {
    return x / (1.f + __expf(-x));
}

// ---------------------------------------------------------------------------
// CSR build (once per call; edge_index is layer-invariant)
// ---------------------------------------------------------------------------
__global__ __launch_bounds__(256) void hist_kernel(
    const int* __restrict__ dst, int* __restrict__ cnt, int E)
{
    for (int e = blockIdx.x * blockDim.x + threadIdx.x; e < E;
         e += gridDim.x * blockDim.x)
        atomicAdd(&cnt[dst[e]], 1);
}

__global__ __launch_bounds__(1024) void scan_kernel(
    const int* __restrict__ cnt, int* __restrict__ off, int N)
{
    __shared__ int ls[1024];
    const int t = threadIdx.x;
    const int C = (N + 1023) >> 10;
    const int lo = t * C;
    const int hi = min(lo + C, N);
    int sum = 0;
    for (int i = lo; i < hi; ++i) sum += cnt[i];
    ls[t] = sum;
    __syncthreads();
    for (int d = 1; d < 1024; d <<= 1) {
        int v = (t >= d) ? ls[t - d] : 0;
        __syncthreads();
        ls[t] += v;
        __syncthreads();
    }
    int excl = (t == 0) ? 0 : ls[t - 1];
    for (int i = lo; i < hi; ++i) { off[i] = excl; excl += cnt[i]; }
    if (t == 1023) off[N] = ls[1023];
}

__global__ __launch_bounds__(256) void scatter2_kernel(
    const int* __restrict__ src, const int* __restrict__ dst,
    int* __restrict__ cursor, int* __restrict__ src_s,
    int* __restrict__ eid_s, int E)
{
    for (int e = blockIdx.x * blockDim.x + threadIdx.x; e < E;
         e += gridDim.x * blockDim.x) {
        const int pos = atomicAdd(&cursor[dst[e]], 1);
        src_s[pos] = src[e];
        eid_s[pos] = e;
    }
}

// ---------------------------------------------------------------------------
// Streaming f32 -> bf16 converts (coalesced both sides)
// ---------------------------------------------------------------------------
__global__ __launch_bounds__(256) void conv_ea(
    const float* __restrict__ ea, unsigned short* __restrict__ ea_b,
    long long total4)
{
    for (long long i = blockIdx.x * 256LL + threadIdx.x; i < total4;
         i += gridDim.x * 256LL) {
        const float4 v = reinterpret_cast<const float4*>(ea)[i];
        ushort4 o;
        o.x = f2bf(v.x); o.y = f2bf(v.y); o.z = f2bf(v.z); o.w = f2bf(v.w);
        reinterpret_cast<ushort4*>(ea_b)[i] = o;
    }
}

__global__ __launch_bounds__(256) void conv_s(
    const float* __restrict__ s0, unsigned int* __restrict__ sbp,
    long long total4)
{
    for (long long i = blockIdx.x * 256LL + threadIdx.x; i < total4;
         i += gridDim.x * 256LL) {
        const float4 v = reinterpret_cast<const float4*>(s0)[i];
        const unsigned a = (unsigned)f2bf(v.x) | ((unsigned)f2bf(v.y) << 16);
        const unsigned b = (unsigned)f2bf(v.z) | ((unsigned)f2bf(v.w) << 16);
        reinterpret_cast<uint2*>(sbp)[i] = make_uint2(a, b);
    }
}

// ---------------------------------------------------------------------------
// We (64x128) -> bf16 B-fragments: frag (kt,ct), lane l holds
// B[k = kt*32 + (l>>4)*8 + j][col = ct*16 + (l&15)], kt<2, ct<8.
// ---------------------------------------------------------------------------
__global__ void prep_we(const float* __restrict__ We, bf16x8* __restrict__ WeB)
{
    const int t = blockIdx.x * blockDim.x + threadIdx.x;
    if (t >= NLAYER * 16 * 64) return;
    const int lane  = t & 63;
    const int frag  = (t >> 6) & 15;
    const int layer = t >> 10;
    const int kt = frag >> 3, ct = frag & 7;
    const int col = ct * 16 + (lane & 15);
    const int k0  = kt * 32 + (lane >> 4) * 8;
    bf16x8 v;
    #pragma unroll
    for (int j = 0; j < 8; ++j)
        v[j] = (__bf16)We[(long long)layer * EDD * HH + (k0 + j) * HH + col];
    WeB[t] = v;
}

// ---------------------------------------------------------------------------
// W (128x128) -> bf16 A^T fragments: frag (kt,ct), kt<4, ct<8; lane l holds
// W[k = kt*32 + (l>>4)*8 + j][outcol = ct*16 + (l&15)].
// ---------------------------------------------------------------------------
__global__ void prep_w128(const float* __restrict__ W, bf16x8* __restrict__ WB)
{
    const int t = blockIdx.x * blockDim.x + threadIdx.x;
    if (t >= NLAYER * 32 * 64) return;
    const int lane  = t & 63;
    const int frag  = (t >> 6) & 31;
    const int layer = t >> 11;
    const int kt = frag >> 3, ct = frag & 7;
    const int col = ct * 16 + (lane & 15);
    const int k0  = kt * 32 + (lane >> 4) * 8;
    bf16x8 v;
    #pragma unroll
    for (int j = 0; j < 8; ++j)
        v[j] = (__bf16)W[(long long)layer * HH * HH + (k0 + j) * HH + col];
    WB[t] = v;
}

// ---------------------------------------------------------------------------
// MFMA aggregation: BLOCK per node (grid-stride), 4 waves split the 8
// col-tiles (2 each) -- the round-6 structure that measured 64% occupancy.
// Single change vs round 6: neighbor features gathered from bf16 shadow sb.
// ---------------------------------------------------------------------------
__global__ __launch_bounds__(256) void gine_agg_mfma(
    const float* __restrict__ s,              // f32 state (self term)
    const unsigned short* __restrict__ sb,    // bf16 shadow of s (gathers)
    const int* __restrict__ src_s,            // dst-sorted src ids, padded
    const int* __restrict__ eid_s,            // dst-sorted edge ids, padded
    const int* __restrict__ off,              // [N+1]
    const unsigned short* __restrict__ ea_b,  // [E][64] bf16, original order
    const bf16x8* __restrict__ WeB,           // this layer's 16 frags
    const float* __restrict__ be,
    float* __restrict__ hbuf,                 // out: s + agg
    int N)
{
    const int wave = threadIdx.x >> 6;   // col-tiles {2*wave, 2*wave+1}
    const int lane = threadIdx.x & 63;
    const int lmod = lane & 15;
    const int ldiv = lane >> 4;

    const bf16x8 wb00 = WeB[(0 * 8 + 2 * wave    ) * 64 + lane];
    const bf16x8 wb01 = WeB[(0 * 8 + 2 * wave + 1) * 64 + lane];
    const bf16x8 wb10 = WeB[(1 * 8 + 2 * wave    ) * 64 + lane];
    const bf16x8 wb11 = WeB[(1 * 8 + 2 * wave + 1) * 64 + lane];

    const int col0 = (2 * wave)     * 16 + lmod;
    const int col1 = (2 * wave + 1) * 16 + lmod;
    const float bev0 = be[col0];
    const float bev1 = be[col1];

    for (int n = blockIdx.x; n < N; n += gridDim.x) {
        const int p0 = off[n], p1 = off[n + 1];
        float acc0 = 0.f, acc1 = 0.f;

        for (int p = p0; p < p1; p += 16) {
            const int rem = p1 - p;
            const int rowid = eid_s[p + lmod];
            const unsigned short* arow =
                ea_b + (long long)rowid * EDD + ldiv * 8;
            const bf16x8 a0 = *reinterpret_cast<const bf16x8*>(arow);
            const bf16x8 a1 = *reinterpret_cast<const bf16x8*>(arow + 32);

            const int ms0 = src_s[p + ldiv * 4 + 0];
            const int ms1 = src_s[p + ldiv * 4 + 1];
            const int ms2 = src_s[p + ldiv * 4 + 2];
            const int ms3 = src_s[p + ldiv * 4 + 3];

            f32x4 c0 = {0.f, 0.f, 0.f, 0.f};
            f32x4 c1 = {0.f, 0.f, 0.f, 0.f};
            c0 = __builtin_amdgcn_mfma_f32_16x16x32_bf16(a0, wb00, c0, 0, 0, 0);
            c0 = __builtin_amdgcn_mfma_f32_16x16x32_bf16(a1, wb10, c0, 0, 0, 0);
            c1 = __builtin_amdgcn_mfma_f32_16x16x32_bf16(a0, wb01, c1, 0, 0, 0);
            c1 = __builtin_amdgcn_mfma_f32_16x16x32_bf16(a1, wb11, c1, 0, 0, 0);

            const int base_row = ldiv * 4;
            const int msv[4] = {ms0, ms1, ms2, ms3};
            #pragma unroll
            for (int r = 0; r < 4; ++r) {
                if (base_row + r < rem) {
                    const long long srow = (long long)msv[r] * HH;
                    const float sv0 = bf2f(sb[srow + col0]);
                    const float sv1 = bf2f(sb[srow + col1]);
                    acc0 += fmaxf(sv0 + c0[r] + bev0, 0.f);
                    acc1 += fmaxf(sv1 + c1[r] + bev1, 0.f);
                }
            }
        }

        acc0 += __shfl_xor(acc0, 16, 64);
        acc0 += __shfl_xor(acc0, 32, 64);
        acc1 += __shfl_xor(acc1, 16, 64);
        acc1 += __shfl_xor(acc1, 32, 64);

        if (ldiv < 2) {
            const int col = (ldiv == 0) ? col0 : col1;
            const float a = (ldiv == 0) ? acc0 : acc1;
            hbuf[(long long)n * HH + col] = s[(long long)n * HH + col] + a;
        }
    }
}

// ---------------------------------------------------------------------------
// MLP stage 1 (MFMA): t1 = silu(h @ W1 + b1)  as  D = W1^T . h^T.
// ---------------------------------------------------------------------------
__global__ __launch_bounds__(256) void gine_mlp1(
    const float* __restrict__ h,       // [N][128] f32
    const bf16x8* __restrict__ W1B,    // this layer's 32 frags
    const float* __restrict__ b1,
    unsigned short* __restrict__ t1,   // [N][128] bf16 out
    int N)
{
    const int wave = threadIdx.x >> 6;
    const int lane = threadIdx.x & 63;
    const int lmod = lane & 15;
    const int ldiv = lane >> 4;

    bf16x8 wf[4][2];
    #pragma unroll
    for (int kt = 0; kt < 4; ++kt) {
        wf[kt][0] = W1B[(kt * 8 + 2 * wave    ) * 64 + lane];
        wf[kt][1] = W1B[(kt * 8 + 2 * wave + 1) * 64 + lane];
    }
    float4 bv[2];
    bv[0] = *reinterpret_cast<const float4*>(&b1[(2 * wave)     * 16 + ldiv * 4]);
    bv[1] = *reinterpret_cast<const float4*>(&b1[(2 * wave + 1) * 16 + ldiv * 4]);

    const int ntiles = (N + 15) >> 4;
    for (int t = blockIdx.x; t < ntiles; t += gridDim.x) {
        const int node = t * 16 + lmod;
        const long long hb = (long long)min(node, N - 1) * HH;

        f32x4 c0 = {0.f, 0.f, 0.f, 0.f};
        f32x4 c1 = {0.f, 0.f, 0.f, 0.f};
        #pragma unroll
        for (int kt = 0; kt < 4; ++kt) {
            const float4 f0 = *reinterpret_cast<const float4*>(&h[hb + kt * 32 + ldiv * 8]);
            const float4 f1 = *reinterpret_cast<const float4*>(&h[hb + kt * 32 + ldiv * 8 + 4]);
            bf16x8 hf;
            hf[0] = (__bf16)f0.x; hf[1] = (__bf16)f0.y;
            hf[2] = (__bf16)f0.z; hf[3] = (__bf16)f0.w;
            hf[4] = (__bf16)f1.x; hf[5] = (__bf16)f1.y;
            hf[6] = (__bf16)f1.z; hf[7] = (__bf16)f1.w;
            c0 = __builtin_amdgcn_mfma_f32_16x16x32_bf16(wf[kt][0], hf, c0, 0, 0, 0);
            c1 = __builtin_amdgcn_mfma_f32_16x16x32_bf16(wf[kt][1], hf, c1, 0, 0, 0);
        }

        if (node < N) {
            const long long tb = (long long)node * HH;
            #pragma unroll
            for (int ctl = 0; ctl < 2; ++ctl) {
                const f32x4 cc = ctl ? c1 : c0;
                const int oc0 = (2 * wave + ctl) * 16 + ldiv * 4;
                const float v0 = silu(cc[0] + (ctl ? bv[1].x : bv[0].x));
                const float v1 = silu(cc[1] + (ctl ? bv[1].y : bv[0].y));
                const float v2 = silu(cc[2] + (ctl ? bv[1].z : bv[0].z));
                const float v3 = silu(cc[3] + (ctl ? bv[1].w : bv[0].w));
                uint2 pk;
                pk.x = (unsigned)f2bf(v0) | ((unsigned)f2bf(v1) << 16);
                pk.y = (unsigned)f2bf(v2) | ((unsigned)f2bf(v3) << 16);
                *reinterpret_cast<uint2*>(&t1[tb + oc0]) = pk;
            }
        }
    }
}

// ---------------------------------------------------------------------------
// MLP stage 2 (MFMA) + residual + LayerNorm + SiLU + bf16 shadow.
// ---------------------------------------------------------------------------
__global__ __launch_bounds__(256) void gine_mlp2(
    const float* __restrict__ s_in,
    const unsigned short* __restrict__ t1,   // [N][128] bf16
    const bf16x8* __restrict__ W2B,
    const float* __restrict__ b2,
    const float* __restrict__ gamma,
    const float* __restrict__ beta,
    float* __restrict__ s_out,
    unsigned short* __restrict__ sb_out,     // bf16 shadow
    int N)
{
    __shared__ float2 red[4][16];

    const int wave = threadIdx.x >> 6;
    const int lane = threadIdx.x & 63;
    const int lmod = lane & 15;
    const int ldiv = lane >> 4;

    bf16x8 wf[4][2];
    #pragma unroll
    for (int kt = 0; kt < 4; ++kt) {
        wf[kt][0] = W2B[(kt * 8 + 2 * wave    ) * 64 + lane];
        wf[kt][1] = W2B[(kt * 8 + 2 * wave + 1) * 64 + lane];
    }
    float4 bv[2], gv[2], ev[2];
    #pragma unroll
    for (int ctl = 0; ctl < 2; ++ctl) {
        const int oc0 = (2 * wave + ctl) * 16 + ldiv * 4;
        bv[ctl] = *reinterpret_cast<const float4*>(&b2[oc0]);
        gv[ctl] = *reinterpret_cast<const float4*>(&gamma[oc0]);
        ev[ctl] = *reinterpret_cast<const float4*>(&beta[oc0]);
    }

    const int ntiles = (N + 15) >> 4;
    for (int t = blockIdx.x; t < ntiles; t += gridDim.x) {
        const int node = t * 16 + lmod;
        const long long nb = (long long)min(node, N - 1) * HH;

        f32x4 c0 = {0.f, 0.f, 0.f, 0.f};
        f32x4 c1 = {0.f, 0.f, 0.f, 0.f};
        #pragma unroll
        for (int kt = 0; kt < 4; ++kt) {
            const bf16x8 tf = *reinterpret_cast<const bf16x8*>(
                &t1[nb + kt * 32 + ldiv * 8]);
            c0 = __builtin_amdgcn_mfma_f32_16x16x32_bf16(wf[kt][0], tf, c0, 0, 0, 0);
            c1 = __builtin_amdgcn_mfma_f32_16x16x32_bf16(wf[kt][1], tf, c1, 0, 0, 0);
        }

        float v[2][4];
        float sum = 0.f, ssq = 0.f;
        #pragma unroll
        for (int ctl = 0; ctl < 2; ++ctl) {
            const int oc0 = (2 * wave + ctl) * 16 + ldiv * 4;
            const float4 sv = *reinterpret_cast<const float4*>(&s_in[nb + oc0]);
            const f32x4 cc = ctl ? c1 : c0;
            v[ctl][0] = sv.x + cc[0] + bv[ctl].x;
            v[ctl][1] = sv.y + cc[1] + bv[ctl].y;
            v[ctl][2] = sv.z + cc[2] + bv[ctl].z;
            v[ctl][3] = sv.w + cc[3] + bv[ctl].w;
            #pragma unroll
            for (int r = 0; r < 4; ++r) { sum += v[ctl][r]; ssq += v[ctl][r] * v[ctl][r]; }
        }
        sum += __shfl_xor(sum, 16, 64); sum += __shfl_xor(sum, 32, 64);
        ssq += __shfl_xor(ssq, 16, 64); ssq += __shfl_xor(ssq, 32, 64);
        if (ldiv == 0) red[wave][lmod] = make_float2(sum, ssq);
        __syncthreads();
        float ts = 0.f, tq = 0.f;
        #pragma unroll
        for (int w = 0; w < 4; ++w) {
            const float2 rr = red[w][lmod];
            ts += rr.x; tq += rr.y;
        }
        __syncthreads();

        const float mu = ts * (1.0f / HH);
        const float var = tq * (1.0f / HH) - mu * mu;
        const float rs = rsqrtf(var + LN_EPS);

        if (node < N) {
            #pragma unroll
            for (int ctl = 0; ctl < 2; ++ctl) {
                const int oc0 = (2 * wave + ctl) * 16 + ldiv * 4;
                float o[4];
                o[0] = silu((v[ctl][0] - mu) * rs * gv[ctl].x + ev[ctl].x);
                o[1] = silu((v[ctl][1] - mu) * rs * gv[ctl].y + ev[ctl].y);
                o[2] = silu((v[ctl][2] - mu) * rs * gv[ctl].z + ev[ctl].z);
                o[3] = silu((v[ctl][3] - mu) * rs * gv[ctl].w + ev[ctl].w);
                *reinterpret_cast<float4*>(&s_out[nb + oc0]) =
                    make_float4(o[0], o[1], o[2], o[3]);
                uint2 pk;
                pk.x = (unsigned)f2bf(o[0]) | ((unsigned)f2bf(o[1]) << 16);
                pk.y = (unsigned)f2bf(o[2]) | ((unsigned)f2bf(o[3]) << 16);
                *reinterpret_cast<uint2*>(&sb_out[nb + oc0]) = pk;
            }
        }
    }
}

// ---------------------------------------------------------------------------
extern "C" void kernel_launch(void* const* d_in, const int* in_sizes, int n_in,
                              void* d_out, int out_size, void* d_ws, size_t ws_size,
                              hipStream_t stream) {
    const float* s0  = (const float*)d_in[0];
    const int*   ei  = (const int*)  d_in[1];
    const float* ea  = (const float*)d_in[2];
    const float* We  = (const float*)d_in[3];
    const float* be  = (const float*)d_in[4];
    const float* W1  = (const float*)d_in[5];
    const float* b1  = (const float*)d_in[6];
    const float* W2  = (const float*)d_in[7];
    const float* b2  = (const float*)d_in[8];
    const float* gm  = (const float*)d_in[9];
    const float* bt  = (const float*)d_in[10];

    const int NH = in_sizes[0];          // N * 128
    const int N  = NH / HH;
    const int E  = in_sizes[1] / 2;
    const int* src = ei;
    const int* dst = ei + E;

    // ws layout; hbuf aliases d_out (mlp1 consumes h before mlp2 writes d_out)
    float*          sbuf  = (float*)d_ws;                       // [N*H] f32
    unsigned short* sb    = (unsigned short*)(sbuf + NH);       // [N*H] bf16 shadow
    unsigned short* t1b   = sb + NH;                            // [N*H] bf16 t1
    unsigned short* ea_b  = t1b + NH;                           // [E*64] bf16
    bf16x8*         WeB   = (bf16x8*)(ea_b + (size_t)E * EDD);  // [3*16*64]
    bf16x8*         W1B   = WeB + NLAYER * 16 * 64;             // [3*32*64]
    bf16x8*         W2B   = W1B + NLAYER * 32 * 64;             // [3*32*64]
    int*            src_s = (int*)(W2B + NLAYER * 32 * 64);     // [E+16]
    int*            eid_s = src_s + (E + 16);                   // [E+16]
    int*            off   = eid_s + (E + 16);                   // [N+1]
    int*            cursor= off + (N + 1);                      // [N] (also cnt)
    float*          hbuf  = (float*)d_out;                      // [N*H] f32

    hipMemcpyAsync(sbuf, s0, sizeof(float) * NH, hipMemcpyDeviceToDevice, stream);

    // ---- one-time preprocessing
    hipMemsetAsync(cursor, 0, sizeof(int) * N, stream);
    hist_kernel<<<1024, 256, 0, stream>>>(dst, cursor, E);
    scan_kernel<<<1, 1024, 0, stream>>>(cursor, off, N);
    hipMemcpyAsync(cursor, off, sizeof(int) * N, hipMemcpyDeviceToDevice, stream);
    scatter2_kernel<<<1024, 256, 0, stream>>>(src, dst, cursor, src_s, eid_s, E);
    hipMemsetAsync(src_s + E, 0, 16 * sizeof(int), stream);
    hipMemsetAsync(eid_s + E, 0, 16 * sizeof(int), stream);
    conv_ea<<<2048, 256, 0, stream>>>(ea, ea_b, (long long)E * EDD / 4);
    conv_s<<<1024, 256, 0, stream>>>(s0, (unsigned int*)sb, (long long)NH / 4);
    prep_we<<<12, 256, 0, stream>>>(We, WeB);
    prep_w128<<<24, 256, 0, stream>>>(W1, W1B);
    prep_w128<<<24, 256, 0, stream>>>(W2, W2B);

    for (int l = 0; l < NLAYER; ++l) {
        gine_agg_mfma<<<4096, 256, 0, stream>>>(sbuf, sb, src_s, eid_s, off, ea_b,
                                                WeB + (size_t)l * 16 * 64,
                                                be + l * HH, hbuf, N);
        gine_mlp1<<<1024, 256, 0, stream>>>(hbuf,
                                            W1B + (size_t)l * 32 * 64,
                                            b1 + l * HH, t1b, N);
        float* sout = (l == NLAYER - 1) ? (float*)d_out : sbuf;
        gine_mlp2<<<1024, 256, 0, stream>>>(sbuf, t1b,
                                            W2B + (size_t)l * 32 * 64,
                                            b2 + l * HH,
                                            gm + l * HH, bt + l * HH,
                                            sout, sb, N);
    }
}

// Round 10
// 736.136 us; speedup vs baseline: 4.0469x; 1.2086x over previous
//
#include <hip/hip_runtime.h>
#include <hip/hip_bf16.h>

#define HH 128   // hidden
#define EDD 64   // edge_dim
#define NLAYER 3
#define LN_EPS 1e-5f
#define LROW 136 // LDS row stride in ushorts (272 B: 16B-aligned, bank-safe)

typedef __attribute__((ext_vector_type(8))) __bf16 bf16x8;
typedef __attribute__((ext_vector_type(4))) float f32x4;

static __device__ __forceinline__ float bf2f(unsigned short u) {
    return __uint_as_float(((unsigned)u) << 16);
}
static __device__ __forceinline__ unsigned short f2bf(float f) {
    return __builtin_bit_cast(unsigned short, (__bf16)f);
}
static __device__ __forceinline__ float silu(float x) {
    return x / (1.f + __expf(-x));
}

// ---------------------------------------------------------------------------
// CSR build (once per call; edge_index is layer-invariant)
// ---------------------------------------------------------------------------
__global__ __launch_bounds__(256) void hist_kernel(
    const int* __restrict__ dst, int* __restrict__ cnt, int E)
{
    for (int e = blockIdx.x * blockDim.x + threadIdx.x; e < E;
         e += gridDim.x * blockDim.x)
        atomicAdd(&cnt[dst[e]], 1);
}

__global__ __launch_bounds__(1024) void scan_kernel(
    const int* __restrict__ cnt, int* __restrict__ off, int N)
{
    __shared__ int ls[1024];
    const int t = threadIdx.x;
    const int C = (N + 1023) >> 10;
    const int lo = t * C;
    const int hi = min(lo + C, N);
    int sum = 0;
    for (int i = lo; i < hi; ++i) sum += cnt[i];
    ls[t] = sum;
    __syncthreads();
    for (int d = 1; d < 1024; d <<= 1) {
        int v = (t >= d) ? ls[t - d] : 0;
        __syncthreads();
        ls[t] += v;
        __syncthreads();
    }
    int excl = (t == 0) ? 0 : ls[t - 1];
    for (int i = lo; i < hi; ++i) { off[i] = excl; excl += cnt[i]; }
    if (t == 1023) off[N] = ls[1023];
}

__global__ __launch_bounds__(256) void scatter2_kernel(
    const int* __restrict__ src, const int* __restrict__ dst,
    int* __restrict__ cursor, int* __restrict__ src_s,
    int* __restrict__ eid_s, int E)
{
    if (blockIdx.x == 0 && threadIdx.x < 16) {   // pad tails
        src_s[E + threadIdx.x] = 0;
        eid_s[E + threadIdx.x] = 0;
    }
    for (int e = blockIdx.x * blockDim.x + threadIdx.x; e < E;
         e += gridDim.x * blockDim.x) {
        const int pos = atomicAdd(&cursor[dst[e]], 1);
        src_s[pos] = src[e];
        eid_s[pos] = e;
    }
}

// ---------------------------------------------------------------------------
// Streaming f32 -> bf16 converts (coalesced both sides)
// ---------------------------------------------------------------------------
__global__ __launch_bounds__(256) void conv_ea(
    const float* __restrict__ ea, unsigned short* __restrict__ ea_b,
    long long total4)
{
    for (long long i = blockIdx.x * 256LL + threadIdx.x; i < total4;
         i += gridDim.x * 256LL) {
        const float4 v = reinterpret_cast<const float4*>(ea)[i];
        ushort4 o;
        o.x = f2bf(v.x); o.y = f2bf(v.y); o.z = f2bf(v.z); o.w = f2bf(v.w);
        reinterpret_cast<ushort4*>(ea_b)[i] = o;
    }
}

__global__ __launch_bounds__(256) void conv_s(
    const float* __restrict__ s0, unsigned int* __restrict__ sbp,
    long long total4)
{
    for (long long i = blockIdx.x * 256LL + threadIdx.x; i < total4;
         i += gridDim.x * 256LL) {
        const float4 v = reinterpret_cast<const float4*>(s0)[i];
        const unsigned a = (unsigned)f2bf(v.x) | ((unsigned)f2bf(v.y) << 16);
        const unsigned b = (unsigned)f2bf(v.z) | ((unsigned)f2bf(v.w) << 16);
        reinterpret_cast<uint2*>(sbp)[i] = make_uint2(a, b);
    }
}

// ---------------------------------------------------------------------------
// We (64x128) -> bf16 B-fragments: frag (kt,ct), lane l holds
// B[k = kt*32 + (l>>4)*8 + j][col = ct*16 + (l&15)], kt<2, ct<8.
// ---------------------------------------------------------------------------
__global__ void prep_we(const float* __restrict__ We, bf16x8* __restrict__ WeB)
{
    const int t = blockIdx.x * blockDim.x + threadIdx.x;
    if (t >= NLAYER * 16 * 64) return;
    const int lane  = t & 63;
    const int frag  = (t >> 6) & 15;
    const int layer = t >> 10;
    const int kt = frag >> 3, ct = frag & 7;
    const int col = ct * 16 + (lane & 15);
    const int k0  = kt * 32 + (lane >> 4) * 8;
    bf16x8 v;
    #pragma unroll
    for (int j = 0; j < 8; ++j)
        v[j] = (__bf16)We[(long long)layer * EDD * HH + (k0 + j) * HH + col];
    WeB[t] = v;
}

// ---------------------------------------------------------------------------
// W (128x128) -> bf16 A^T fragments: frag (kt,ct), kt<4, ct<8; lane l holds
// W[k = kt*32 + (l>>4)*8 + j][outcol = ct*16 + (l&15)].
// ---------------------------------------------------------------------------
__global__ void prep_w128(const float* __restrict__ W, bf16x8* __restrict__ WB)
{
    const int t = blockIdx.x * blockDim.x + threadIdx.x;
    if (t >= NLAYER * 32 * 64) return;
    const int lane  = t & 63;
    const int frag  = (t >> 6) & 31;
    const int layer = t >> 11;
    const int kt = frag >> 3, ct = frag & 7;
    const int col = ct * 16 + (lane & 15);
    const int k0  = kt * 32 + (lane >> 4) * 8;
    bf16x8 v;
    #pragma unroll
    for (int j = 0; j < 8; ++j)
        v[j] = (__bf16)W[(long long)layer * HH * HH + (k0 + j) * HH + col];
    WB[t] = v;
}

// ---------------------------------------------------------------------------
// MFMA aggregation, LDS-staged gathers. Block per node (grid-stride), 4 waves
// split 8 col-tiles. Per 16-edge chunk: 256 threads cooperatively stage the 16
// src rows (one uint4/thread, 4-segment gathers) into a bank-padded LDS tile;
// each wave then reads its columns via ds_read_u16 (off the TA path).
// Output h = s + agg written directly as bf16 (what mlp1 consumes anyway).
// ---------------------------------------------------------------------------
__global__ __launch_bounds__(256) void gine_agg_mfma(
    const float* __restrict__ s,              // f32 state (self term)
    const unsigned short* __restrict__ sb,    // bf16 shadow of s (gathers)
    const int* __restrict__ src_s,            // dst-sorted src ids, padded
    const int* __restrict__ eid_s,            // dst-sorted edge ids, padded
    const int* __restrict__ off,              // [N+1]
    const unsigned short* __restrict__ ea_b,  // [E][64] bf16, original order
    const bf16x8* __restrict__ WeB,           // this layer's 16 frags
    const float* __restrict__ be,
    unsigned short* __restrict__ hb16,        // out: bf16(s + agg)
    int N)
{
    __shared__ unsigned short lsb[16 * LROW];   // 16 src rows, 272B stride

    const int tid  = threadIdx.x;
    const int wave = tid >> 6;   // col-tiles {2*wave, 2*wave+1}
    const int lane = tid & 63;
    const int lmod = lane & 15;
    const int ldiv = lane >> 4;

    const bf16x8 wb00 = WeB[(0 * 8 + 2 * wave    ) * 64 + lane];
    const bf16x8 wb01 = WeB[(0 * 8 + 2 * wave + 1) * 64 + lane];
    const bf16x8 wb10 = WeB[(1 * 8 + 2 * wave    ) * 64 + lane];
    const bf16x8 wb11 = WeB[(1 * 8 + 2 * wave + 1) * 64 + lane];

    const int col0 = (2 * wave) * 16 + lmod;
    const int col1 = col0 + 16;
    const float bev0 = be[col0];
    const float bev1 = be[col1];

    const int stg_row = tid >> 4;   // 0..15: which src row this thread stages
    const int stg_seg = tid & 15;   // 16B segment within the 256B row

    for (int n = blockIdx.x; n < N; n += gridDim.x) {
        const int p0 = off[n], p1 = off[n + 1];
        float acc0 = 0.f, acc1 = 0.f;

        for (int p = p0; p < p1; p += 16) {
            const int rem = p1 - p;

            // issue the staging gather early (latency overlaps barrier+A-load)
            const int snode = src_s[p + stg_row];
            const uint4 sv4 = *reinterpret_cast<const uint4*>(
                &sb[(long long)snode * HH + stg_seg * 8]);

            __syncthreads();   // previous chunk's readers done with lsb
            *reinterpret_cast<uint4*>(&lsb[stg_row * LROW + stg_seg * 8]) = sv4;

            // A fragment (edge attrs), eid-indirect
            const int rowid = eid_s[p + lmod];
            const unsigned short* arow = ea_b + (long long)rowid * EDD + ldiv * 8;
            const bf16x8 a0 = *reinterpret_cast<const bf16x8*>(arow);
            const bf16x8 a1 = *reinterpret_cast<const bf16x8*>(arow + 32);

            f32x4 c0 = {0.f, 0.f, 0.f, 0.f};
            f32x4 c1 = {0.f, 0.f, 0.f, 0.f};
            c0 = __builtin_amdgcn_mfma_f32_16x16x32_bf16(a0, wb00, c0, 0, 0, 0);
            c0 = __builtin_amdgcn_mfma_f32_16x16x32_bf16(a1, wb10, c0, 0, 0, 0);
            c1 = __builtin_amdgcn_mfma_f32_16x16x32_bf16(a0, wb01, c1, 0, 0, 0);
            c1 = __builtin_amdgcn_mfma_f32_16x16x32_bf16(a1, wb11, c1, 0, 0, 0);

            __syncthreads();   // lsb fully staged

            #pragma unroll
            for (int r = 0; r < 4; ++r) {
                if (ldiv * 4 + r < rem) {
                    const int lr = (ldiv * 4 + r) * LROW;
                    acc0 += fmaxf(bf2f(lsb[lr + col0]) + c0[r] + bev0, 0.f);
                    acc1 += fmaxf(bf2f(lsb[lr + col1]) + c1[r] + bev1, 0.f);
                }
            }
        }

        acc0 += __shfl_xor(acc0, 16, 64);
        acc0 += __shfl_xor(acc0, 32, 64);
        acc1 += __shfl_xor(acc1, 16, 64);
        acc1 += __shfl_xor(acc1, 32, 64);

        if (ldiv < 2) {
            const int col = (ldiv == 0) ? col0 : col1;
            const float a = (ldiv == 0) ? acc0 : acc1;
            hb16[(long long)n * HH + col] =
                f2bf(s[(long long)n * HH + col] + a);
        }
    }
}

// ---------------------------------------------------------------------------
// MLP stage 1 (MFMA): t1 = silu(h @ W1 + b1)  as  D = W1^T . h^T.
// h now arrives as bf16 (written by agg) -> direct fragment loads.
// ---------------------------------------------------------------------------
__global__ __launch_bounds__(256) void gine_mlp1(
    const unsigned short* __restrict__ h16,  // [N][128] bf16
    const bf16x8* __restrict__ W1B,          // this layer's 32 frags
    const float* __restrict__ b1,
    unsigned short* __restrict__ t1,         // [N][128] bf16 out
    int N)
{
    const int wave = threadIdx.x >> 6;
    const int lane = threadIdx.x & 63;
    const int lmod = lane & 15;
    const int ldiv = lane >> 4;

    bf16x8 wf[4][2];
    #pragma unroll
    for (int kt = 0; kt < 4; ++kt) {
        wf[kt][0] = W1B[(kt * 8 + 2 * wave    ) * 64 + lane];
        wf[kt][1] = W1B[(kt * 8 + 2 * wave + 1) * 64 + lane];
    }
    float4 bv[2];
    bv[0] = *reinterpret_cast<const float4*>(&b1[(2 * wave)     * 16 + ldiv * 4]);
    bv[1] = *reinterpret_cast<const float4*>(&b1[(2 * wave + 1) * 16 + ldiv * 4]);

    const int ntiles = (N + 15) >> 4;
    for (int t = blockIdx.x; t < ntiles; t += gridDim.x) {
        const int node = t * 16 + lmod;
        const long long hb = (long long)min(node, N - 1) * HH;

        f32x4 c0 = {0.f, 0.f, 0.f, 0.f};
        f32x4 c1 = {0.f, 0.f, 0.f, 0.f};
        #pragma unroll
        for (int kt = 0; kt < 4; ++kt) {
            const bf16x8 hf = *reinterpret_cast<const bf16x8*>(
                &h16[hb + kt * 32 + ldiv * 8]);
            c0 = __builtin_amdgcn_mfma_f32_16x16x32_bf16(wf[kt][0], hf, c0, 0, 0, 0);
            c1 = __builtin_amdgcn_mfma_f32_16x16x32_bf16(wf[kt][1], hf, c1, 0, 0, 0);
        }

        if (node < N) {
            const long long tb = (long long)node * HH;
            #pragma unroll
            for (int ctl = 0; ctl < 2; ++ctl) {
                const f32x4 cc = ctl ? c1 : c0;
                const int oc0 = (2 * wave + ctl) * 16 + ldiv * 4;
                const float v0 = silu(cc[0] + (ctl ? bv[1].x : bv[0].x));
                const float v1 = silu(cc[1] + (ctl ? bv[1].y : bv[0].y));
                const float v2 = silu(cc[2] + (ctl ? bv[1].z : bv[0].z));
                const float v3 = silu(cc[3] + (ctl ? bv[1].w : bv[0].w));
                uint2 pk;
                pk.x = (unsigned)f2bf(v0) | ((unsigned)f2bf(v1) << 16);
                pk.y = (unsigned)f2bf(v2) | ((unsigned)f2bf(v3) << 16);
                *reinterpret_cast<uint2*>(&t1[tb + oc0]) = pk;
            }
        }
    }
}

// ---------------------------------------------------------------------------
// MLP stage 2 (MFMA) + residual + LayerNorm + SiLU + bf16 shadow.
// ---------------------------------------------------------------------------
__global__ __launch_bounds__(256) void gine_mlp2(
    const float* __restrict__ s_in,
    const unsigned short* __restrict__ t1,   // [N][128] bf16
    const bf16x8* __restrict__ W2B,
    const float* __restrict__ b2,
    const float* __restrict__ gamma,
    const float* __restrict__ beta,
    float* __restrict__ s_out,
    unsigned short* __restrict__ sb_out,     // bf16 shadow
    int N)
{
    __shared__ float2 red[4][16];

    const int wave = threadIdx.x >> 6;
    const int lane = threadIdx.x & 63;
    const int lmod = lane & 15;
    const int ldiv = lane >> 4;

    bf16x8 wf[4][2];
    #pragma unroll
    for (int kt = 0; kt < 4; ++kt) {
        wf[kt][0] = W2B[(kt * 8 + 2 * wave    ) * 64 + lane];
        wf[kt][1] = W2B[(kt * 8 + 2 * wave + 1) * 64 + lane];
    }
    float4 bv[2], gv[2], ev[2];
    #pragma unroll
    for (int ctl = 0; ctl < 2; ++ctl) {
        const int oc0 = (2 * wave + ctl) * 16 + ldiv * 4;
        bv[ctl] = *reinterpret_cast<const float4*>(&b2[oc0]);
        gv[ctl] = *reinterpret_cast<const float4*>(&gamma[oc0]);
        ev[ctl] = *reinterpret_cast<const float4*>(&beta[oc0]);
    }

    const int ntiles = (N + 15) >> 4;
    for (int t = blockIdx.x; t < ntiles; t += gridDim.x) {
        const int node = t * 16 + lmod;
        const long long nb = (long long)min(node, N - 1) * HH;

        f32x4 c0 = {0.f, 0.f, 0.f, 0.f};
        f32x4 c1 = {0.f, 0.f, 0.f, 0.f};
        #pragma unroll
        for (int kt = 0; kt < 4; ++kt) {
            const bf16x8 tf = *reinterpret_cast<const bf16x8*>(
                &t1[nb + kt * 32 + ldiv * 8]);
            c0 = __builtin_amdgcn_mfma_f32_16x16x32_bf16(wf[kt][0], tf, c0, 0, 0, 0);
            c1 = __builtin_amdgcn_mfma_f32_16x16x32_bf16(wf[kt][1], tf, c1, 0, 0, 0);
        }

        float v[2][4];
        float sum = 0.f, ssq = 0.f;
        #pragma unroll
        for (int ctl = 0; ctl < 2; ++ctl) {
            const int oc0 = (2 * wave + ctl) * 16 + ldiv * 4;
            const float4 sv = *reinterpret_cast<const float4*>(&s_in[nb + oc0]);
            const f32x4 cc = ctl ? c1 : c0;
            v[ctl][0] = sv.x + cc[0] + bv[ctl].x;
            v[ctl][1] = sv.y + cc[1] + bv[ctl].y;
            v[ctl][2] = sv.z + cc[2] + bv[ctl].z;
            v[ctl][3] = sv.w + cc[3] + bv[ctl].w;
            #pragma unroll
            for (int r = 0; r < 4; ++r) { sum += v[ctl][r]; ssq += v[ctl][r] * v[ctl][r]; }
        }
        sum += __shfl_xor(sum, 16, 64); sum += __shfl_xor(sum, 32, 64);
        ssq += __shfl_xor(ssq, 16, 64); ssq += __shfl_xor(ssq, 32, 64);
        if (ldiv == 0) red[wave][lmod] = make_float2(sum, ssq);
        __syncthreads();
        float ts = 0.f, tq = 0.f;
        #pragma unroll
        for (int w = 0; w < 4; ++w) {
            const float2 rr = red[w][lmod];
            ts += rr.x; tq += rr.y;
        }
        __syncthreads();

        const float mu = ts * (1.0f / HH);
        const float var = tq * (1.0f / HH) - mu * mu;
        const float rs = rsqrtf(var + LN_EPS);

        if (node < N) {
            #pragma unroll
            for (int ctl = 0; ctl < 2; ++ctl) {
                const int oc0 = (2 * wave + ctl) * 16 + ldiv * 4;
                float o[4];
                o[0] = silu((v[ctl][0] - mu) * rs * gv[ctl].x + ev[ctl].x);
                o[1] = silu((v[ctl][1] - mu) * rs * gv[ctl].y + ev[ctl].y);
                o[2] = silu((v[ctl][2] - mu) * rs * gv[ctl].z + ev[ctl].z);
                o[3] = silu((v[ctl][3] - mu) * rs * gv[ctl].w + ev[ctl].w);
                *reinterpret_cast<float4*>(&s_out[nb + oc0]) =
                    make_float4(o[0], o[1], o[2], o[3]);
                uint2 pk;
                pk.x = (unsigned)f2bf(o[0]) | ((unsigned)f2bf(o[1]) << 16);
                pk.y = (unsigned)f2bf(o[2]) | ((unsigned)f2bf(o[3]) << 16);
                *reinterpret_cast<uint2*>(&sb_out[nb + oc0]) = pk;
            }
        }
    }
}

// ---------------------------------------------------------------------------
extern "C" void kernel_launch(void* const* d_in, const int* in_sizes, int n_in,
                              void* d_out, int out_size, void* d_ws, size_t ws_size,
                              hipStream_t stream) {
    const float* s0  = (const float*)d_in[0];
    const int*   ei  = (const int*)  d_in[1];
    const float* ea  = (const float*)d_in[2];
    const float* We  = (const float*)d_in[3];
    const float* be  = (const float*)d_in[4];
    const float* W1  = (const float*)d_in[5];
    const float* b1  = (const float*)d_in[6];
    const float* W2  = (const float*)d_in[7];
    const float* b2  = (const float*)d_in[8];
    const float* gm  = (const float*)d_in[9];
    const float* bt  = (const float*)d_in[10];

    const int NH = in_sizes[0];          // N * 128
    const int N  = NH / HH;
    const int E  = in_sizes[1] / 2;
    const int* src = ei;
    const int* dst = ei + E;

    // ws layout
    float*          sbuf  = (float*)d_ws;                       // [N*H] f32
    unsigned short* sb    = (unsigned short*)(sbuf + NH);       // [N*H] bf16 shadow
    unsigned short* t1b   = sb + NH;                            // [N*H] bf16 t1
    unsigned short* hb16  = t1b + NH;                           // [N*H] bf16 h
    unsigned short* ea_b  = hb16 + NH;                          // [E*64] bf16
    bf16x8*         WeB   = (bf16x8*)(ea_b + (size_t)E * EDD);  // [3*16*64]
    bf16x8*         W1B   = WeB + NLAYER * 16 * 64;             // [3*32*64]
    bf16x8*         W2B   = W1B + NLAYER * 32 * 64;             // [3*32*64]
    int*            src_s = (int*)(W2B + NLAYER * 32 * 64);     // [E+16]
    int*            eid_s = src_s + (E + 16);                   // [E+16]
    int*            off   = eid_s + (E + 16);                   // [N+1]
    int*            cursor= off + (N + 1);                      // [N] (also cnt)

    hipMemcpyAsync(sbuf, s0, sizeof(float) * NH, hipMemcpyDeviceToDevice, stream);

    // ---- one-time preprocessing
    hipMemsetAsync(cursor, 0, sizeof(int) * N, stream);
    hist_kernel<<<1024, 256, 0, stream>>>(dst, cursor, E);
    scan_kernel<<<1, 1024, 0, stream>>>(cursor, off, N);
    hipMemcpyAsync(cursor, off, sizeof(int) * N, hipMemcpyDeviceToDevice, stream);
    scatter2_kernel<<<1024, 256, 0, stream>>>(src, dst, cursor, src_s, eid_s, E);
    conv_ea<<<2048, 256, 0, stream>>>(ea, ea_b, (long long)E * EDD / 4);
    conv_s<<<1024, 256, 0, stream>>>(s0, (unsigned int*)sb, (long long)NH / 4);
    prep_we<<<12, 256, 0, stream>>>(We, WeB);
    prep_w128<<<24, 256, 0, stream>>>(W1, W1B);
    prep_w128<<<24, 256, 0, stream>>>(W2, W2B);

    for (int l = 0; l < NLAYER; ++l) {
        gine_agg_mfma<<<4096, 256, 0, stream>>>(sbuf, sb, src_s, eid_s, off, ea_b,
                                                WeB + (size_t)l * 16 * 64,
                                                be + l * HH, hb16, N);
        gine_mlp1<<<1024, 256, 0, stream>>>(hb16,
                                            W1B + (size_t)l * 32 * 64,
                                            b1 + l * HH, t1b, N);
        float* sout = (l == NLAYER - 1) ? (float*)d_out : sbuf;
        gine_mlp2<<<1024, 256, 0, stream>>>(sbuf, t1b,
                                            W2B + (size_t)l * 32 * 64,
                                            b2 + l * HH,
                                            gm + l * HH, bt + l * HH,
                                            sout, sb, N);
    }
}

// Round 11
// 652.423 us; speedup vs baseline: 4.5662x; 1.1283x over previous
//
#include <hip/hip_runtime.h>
#include <hip/hip_bf16.h>

#define HH 128   // hidden
#define EDD 64   // edge_dim
#define NLAYER 3
#define LN_EPS 1e-5f
#define LROW 136 // LDS row stride in ushorts (272 B: 16B-aligned, bank-safe)

typedef __attribute__((ext_vector_type(8))) __bf16 bf16x8;
typedef __attribute__((ext_vector_type(4))) float f32x4;

static __device__ __forceinline__ float bf2f(unsigned short u) {
    return __uint_as_float(((unsigned)u) << 16);
}
static __device__ __forceinline__ unsigned short f2bf(float f) {
    return __builtin_bit_cast(unsigned short, (__bf16)f);
}
static __device__ __forceinline__ float silu(float x) {
    return x / (1.f + __expf(-x));
}

// ---------------------------------------------------------------------------
// CSR build (once per call; edge_index is layer-invariant)
// ---------------------------------------------------------------------------
__global__ __launch_bounds__(256) void hist_kernel(
    const int* __restrict__ dst, int* __restrict__ cnt, int E)
{
    for (int e = blockIdx.x * blockDim.x + threadIdx.x; e < E;
         e += gridDim.x * blockDim.x)
        atomicAdd(&cnt[dst[e]], 1);
}

__global__ __launch_bounds__(1024) void scan_kernel(
    const int* __restrict__ cnt, int* __restrict__ off, int N)
{
    __shared__ int ls[1024];
    const int t = threadIdx.x;
    const int C = (N + 1023) >> 10;
    const int lo = t * C;
    const int hi = min(lo + C, N);
    int sum = 0;
    for (int i = lo; i < hi; ++i) sum += cnt[i];
    ls[t] = sum;
    __syncthreads();
    for (int d = 1; d < 1024; d <<= 1) {
        int v = (t >= d) ? ls[t - d] : 0;
        __syncthreads();
        ls[t] += v;
        __syncthreads();
    }
    int excl = (t == 0) ? 0 : ls[t - 1];
    for (int i = lo; i < hi; ++i) { off[i] = excl; excl += cnt[i]; }
    if (t == 1023) off[N] = ls[1023];
}

__global__ __launch_bounds__(256) void scatter2_kernel(
    const int* __restrict__ src, const int* __restrict__ dst,
    int* __restrict__ cursor, int* __restrict__ src_s,
    int* __restrict__ eid_s, int E)
{
    if (blockIdx.x == 0 && threadIdx.x < 16) {   // pad tails
        src_s[E + threadIdx.x] = 0;
        eid_s[E + threadIdx.x] = 0;
    }
    for (int e = blockIdx.x * blockDim.x + threadIdx.x; e < E;
         e += gridDim.x * blockDim.x) {
        const int pos = atomicAdd(&cursor[dst[e]], 1);
        src_s[pos] = src[e];
        eid_s[pos] = e;
    }
}

// ---------------------------------------------------------------------------
// Streaming f32 -> bf16 converts (coalesced both sides)
// ---------------------------------------------------------------------------
__global__ __launch_bounds__(256) void conv_ea(
    const float* __restrict__ ea, unsigned short* __restrict__ ea_b,
    long long total4)
{
    for (long long i = blockIdx.x * 256LL + threadIdx.x; i < total4;
         i += gridDim.x * 256LL) {
        const float4 v = reinterpret_cast<const float4*>(ea)[i];
        ushort4 o;
        o.x = f2bf(v.x); o.y = f2bf(v.y); o.z = f2bf(v.z); o.w = f2bf(v.w);
        reinterpret_cast<ushort4*>(ea_b)[i] = o;
    }
}

__global__ __launch_bounds__(256) void conv_s(
    const float* __restrict__ s0, unsigned int* __restrict__ sbp,
    long long total4)
{
    for (long long i = blockIdx.x * 256LL + threadIdx.x; i < total4;
         i += gridDim.x * 256LL) {
        const float4 v = reinterpret_cast<const float4*>(s0)[i];
        const unsigned a = (unsigned)f2bf(v.x) | ((unsigned)f2bf(v.y) << 16);
        const unsigned b = (unsigned)f2bf(v.z) | ((unsigned)f2bf(v.w) << 16);
        reinterpret_cast<uint2*>(sbp)[i] = make_uint2(a, b);
    }
}

// ---------------------------------------------------------------------------
// We (64x128) -> bf16 B-fragments: frag (kt,ct), lane l holds
// B[k = kt*32 + (l>>4)*8 + j][col = ct*16 + (l&15)], kt<2, ct<8.
// ---------------------------------------------------------------------------
__global__ void prep_we(const float* __restrict__ We, bf16x8* __restrict__ WeB)
{
    const int t = blockIdx.x * blockDim.x + threadIdx.x;
    if (t >= NLAYER * 16 * 64) return;
    const int lane  = t & 63;
    const int frag  = (t >> 6) & 15;
    const int layer = t >> 10;
    const int kt = frag >> 3, ct = frag & 7;
    const int col = ct * 16 + (lane & 15);
    const int k0  = kt * 32 + (lane >> 4) * 8;
    bf16x8 v;
    #pragma unroll
    for (int j = 0; j < 8; ++j)
        v[j] = (__bf16)We[(long long)layer * EDD * HH + (k0 + j) * HH + col];
    WeB[t] = v;
}

// ---------------------------------------------------------------------------
// W (128x128) -> bf16 A^T fragments: frag (kt,ct), kt<4, ct<8; lane l holds
// W[k = kt*32 + (l>>4)*8 + j][outcol = ct*16 + (l&15)].
// ---------------------------------------------------------------------------
__global__ void prep_w128(const float* __restrict__ W, bf16x8* __restrict__ WB)
{
    const int t = blockIdx.x * blockDim.x + threadIdx.x;
    if (t >= NLAYER * 32 * 64) return;
    const int lane  = t & 63;
    const int frag  = (t >> 6) & 31;
    const int layer = t >> 11;
    const int kt = frag >> 3, ct = frag & 7;
    const int col = ct * 16 + (lane & 15);
    const int k0  = kt * 32 + (lane >> 4) * 8;
    bf16x8 v;
    #pragma unroll
    for (int j = 0; j < 8; ++j)
        v[j] = (__bf16)W[(long long)layer * HH * HH + (k0 + j) * HH + col];
    WB[t] = v;
}

// ---------------------------------------------------------------------------
// MFMA aggregation: TWO NODES PER BLOCK. Waves {0,1} -> node0, {2,3} -> node1
// (wave&1 selects the 64-col half = 4 col-tiles). Per 16-edge chunk, 128
// threads stage each node's 16 src rows (2x uint4/thread) into its LDS tile;
// doubles the memory in flight per barrier period vs one-node blocks.
// Output h = s + agg written directly as bf16.
// ---------------------------------------------------------------------------
__global__ __launch_bounds__(256) void gine_agg_mfma(
    const float* __restrict__ s,              // f32 state (self term)
    const unsigned short* __restrict__ sb,    // bf16 shadow of s (gathers)
    const int* __restrict__ src_s,            // dst-sorted src ids, padded
    const int* __restrict__ eid_s,            // dst-sorted edge ids, padded
    const int* __restrict__ off,              // [N+1]
    const unsigned short* __restrict__ ea_b,  // [E][64] bf16, original order
    const bf16x8* __restrict__ WeB,           // this layer's 16 frags
    const float* __restrict__ be,
    unsigned short* __restrict__ hb16,        // out: bf16(s + agg)
    int N, int E)
{
    __shared__ unsigned short lsb[2][16 * LROW];   // 2 nodes x 16 rows

    const int tid  = threadIdx.x;
    const int wave = tid >> 6;
    const int half = wave & 1;    // column half: cols [half*64, half*64+64)
    const int slot = wave >> 1;   // node slot 0/1
    const int lane = tid & 63;
    const int lmod = lane & 15;
    const int ldiv = lane >> 4;

    bf16x8 wb0[4], wb1[4];
    #pragma unroll
    for (int c = 0; c < 4; ++c) {
        wb0[c] = WeB[(0 * 8 + half * 4 + c) * 64 + lane];
        wb1[c] = WeB[(1 * 8 + half * 4 + c) * 64 + lane];
    }
    float bev[4];
    #pragma unroll
    for (int c = 0; c < 4; ++c) bev[c] = be[(half * 4 + c) * 16 + lmod];

    // staging role: 128 threads per node tile; 2x uint4 (32B) per thread
    const int st_slot = tid >> 7;         // which node's tile
    const int st_row  = (tid >> 3) & 15;  // src row 0..15
    const int st_sp   = tid & 7;          // seg-pair -> ushort offset st_sp*16

    for (int base = blockIdx.x * 2; base < N; base += gridDim.x * 2) {
        const int n0 = base;
        const int n1 = (base + 1 < N) ? base + 1 : base;
        const int q0 = off[n0], q0e = off[n0 + 1];
        const int q1 = off[n1], q1e = off[n1 + 1];
        const int iters = max((q0e - q0 + 15) >> 4, (q1e - q1 + 15) >> 4);

        const int myn = slot ? n1 : n0;
        const int p0  = slot ? q1 : q0;
        const int p1  = slot ? q1e : q0e;
        const int sp0 = st_slot ? q1 : q0;

        float acc[4] = {0.f, 0.f, 0.f, 0.f};

        for (int it = 0; it < iters; ++it) {
            // issue staging gather early (latency overlaps barrier wait)
            const int sidx  = min(sp0 + it * 16 + st_row, E + 15);
            const int snode = src_s[sidx];
            const unsigned short* srow = &sb[(long long)snode * HH + st_sp * 16];
            const uint4 sva = *reinterpret_cast<const uint4*>(srow);
            const uint4 svb = *reinterpret_cast<const uint4*>(srow + 8);

            __syncthreads();   // previous chunk's readers done with lsb
            unsigned short* drow = &lsb[st_slot][st_row * LROW + st_sp * 16];
            *reinterpret_cast<uint4*>(drow)     = sva;
            *reinterpret_cast<uint4*>(drow + 8) = svb;

            // A fragment (edge attrs) for my node, eid-indirect
            const int p   = p0 + it * 16;
            const int rem = p1 - p;
            const int rowid = eid_s[min(p + lmod, E + 15)];
            const unsigned short* arow = ea_b + (long long)rowid * EDD + ldiv * 8;
            const bf16x8 a0 = *reinterpret_cast<const bf16x8*>(arow);
            const bf16x8 a1 = *reinterpret_cast<const bf16x8*>(arow + 32);

            f32x4 cf[4];
            #pragma unroll
            for (int c = 0; c < 4; ++c) {
                f32x4 z = {0.f, 0.f, 0.f, 0.f};
                z = __builtin_amdgcn_mfma_f32_16x16x32_bf16(a0, wb0[c], z, 0, 0, 0);
                z = __builtin_amdgcn_mfma_f32_16x16x32_bf16(a1, wb1[c], z, 0, 0, 0);
                cf[c] = z;
            }

            __syncthreads();   // lsb fully staged

            #pragma unroll
            for (int r = 0; r < 4; ++r) {
                if (ldiv * 4 + r < rem) {
                    const unsigned short* lr = &lsb[slot][(ldiv * 4 + r) * LROW];
                    #pragma unroll
                    for (int c = 0; c < 4; ++c) {
                        acc[c] += fmaxf(
                            bf2f(lr[(half * 4 + c) * 16 + lmod]) + cf[c][r] + bev[c],
                            0.f);
                    }
                }
            }
        }

        #pragma unroll
        for (int c = 0; c < 4; ++c) {
            acc[c] += __shfl_xor(acc[c], 16, 64);
            acc[c] += __shfl_xor(acc[c], 32, 64);
        }
        // lane (ldiv,lmod) writes col-tile (half*4 + ldiv): one store per lane
        const float av = (ldiv == 0) ? acc[0] : (ldiv == 1) ? acc[1]
                       : (ldiv == 2) ? acc[2] : acc[3];
        const int col = (half * 4 + ldiv) * 16 + lmod;
        const long long nb = (long long)myn * HH;
        hb16[nb + col] = f2bf(s[nb + col] + av);
    }
}

// ---------------------------------------------------------------------------
// Fused node MLP (both MFMA stages):
//   t1 = silu(h@W1+b1)  -> LDS tile -> v = s + t1@W2 + b2
//   s_out = silu(LN(v)*gamma+beta); also writes bf16 shadow.
// Saves the t1 HBM round-trip and one launch per layer.
// ---------------------------------------------------------------------------
__global__ __launch_bounds__(256) void gine_mlp(
    const float* __restrict__ s_in,
    const unsigned short* __restrict__ h16,  // [N][128] bf16 (from agg)
    const bf16x8* __restrict__ W1B, const float* __restrict__ b1,
    const bf16x8* __restrict__ W2B, const float* __restrict__ b2,
    const float* __restrict__ gamma, const float* __restrict__ beta,
    float* __restrict__ s_out,
    unsigned short* __restrict__ sb_out,     // bf16 shadow
    int N)
{
    __shared__ unsigned short t1t[16 * LROW];   // 16 nodes x 128 cols
    __shared__ float2 red[4][16];

    const int wave = threadIdx.x >> 6;
    const int lane = threadIdx.x & 63;
    const int lmod = lane & 15;
    const int ldiv = lane >> 4;

    bf16x8 wf1[4][2], wf2[4][2];
    #pragma unroll
    for (int kt = 0; kt < 4; ++kt) {
        wf1[kt][0] = W1B[(kt * 8 + 2 * wave    ) * 64 + lane];
        wf1[kt][1] = W1B[(kt * 8 + 2 * wave + 1) * 64 + lane];
        wf2[kt][0] = W2B[(kt * 8 + 2 * wave    ) * 64 + lane];
        wf2[kt][1] = W2B[(kt * 8 + 2 * wave + 1) * 64 + lane];
    }
    float4 b1v[2], b2v[2], gv[2], ev[2];
    #pragma unroll
    for (int ctl = 0; ctl < 2; ++ctl) {
        const int oc0 = (2 * wave + ctl) * 16 + ldiv * 4;
        b1v[ctl] = *reinterpret_cast<const float4*>(&b1[oc0]);
        b2v[ctl] = *reinterpret_cast<const float4*>(&b2[oc0]);
        gv[ctl]  = *reinterpret_cast<const float4*>(&gamma[oc0]);
        ev[ctl]  = *reinterpret_cast<const float4*>(&beta[oc0]);
    }

    const int ntiles = (N + 15) >> 4;
    for (int t = blockIdx.x; t < ntiles; t += gridDim.x) {
        const int node = t * 16 + lmod;
        const long long nb = (long long)min(node, N - 1) * HH;

        // ---- stage 1: t1 = silu(h @ W1 + b1)
        f32x4 c0 = {0.f, 0.f, 0.f, 0.f};
        f32x4 c1 = {0.f, 0.f, 0.f, 0.f};
        #pragma unroll
        for (int kt = 0; kt < 4; ++kt) {
            const bf16x8 hf = *reinterpret_cast<const bf16x8*>(
                &h16[nb + kt * 32 + ldiv * 8]);
            c0 = __builtin_amdgcn_mfma_f32_16x16x32_bf16(wf1[kt][0], hf, c0, 0, 0, 0);
            c1 = __builtin_amdgcn_mfma_f32_16x16x32_bf16(wf1[kt][1], hf, c1, 0, 0, 0);
        }
        #pragma unroll
        for (int ctl = 0; ctl < 2; ++ctl) {
            const f32x4 cc = ctl ? c1 : c0;
            const float4 bb = ctl ? b1v[1] : b1v[0];
            uint2 pk;
            pk.x = (unsigned)f2bf(silu(cc[0] + bb.x)) |
                   ((unsigned)f2bf(silu(cc[1] + bb.y)) << 16);
            pk.y = (unsigned)f2bf(silu(cc[2] + bb.z)) |
                   ((unsigned)f2bf(silu(cc[3] + bb.w)) << 16);
            const int oc0 = (2 * wave + ctl) * 16 + ldiv * 4;
            *reinterpret_cast<uint2*>(&t1t[lmod * LROW + oc0]) = pk;
        }
        __syncthreads();   // t1 tile complete

        // ---- stage 2: v = s + t1 @ W2 + b2
        f32x4 d0 = {0.f, 0.f, 0.f, 0.f};
        f32x4 d1 = {0.f, 0.f, 0.f, 0.f};
        #pragma unroll
        for (int kt = 0; kt < 4; ++kt) {
            const bf16x8 tf = *reinterpret_cast<const bf16x8*>(
                &t1t[lmod * LROW + kt * 32 + ldiv * 8]);
            d0 = __builtin_amdgcn_mfma_f32_16x16x32_bf16(wf2[kt][0], tf, d0, 0, 0, 0);
            d1 = __builtin_amdgcn_mfma_f32_16x16x32_bf16(wf2[kt][1], tf, d1, 0, 0, 0);
        }

        float v[2][4];
        float sum = 0.f, ssq = 0.f;
        #pragma unroll
        for (int ctl = 0; ctl < 2; ++ctl) {
            const int oc0 = (2 * wave + ctl) * 16 + ldiv * 4;
            const float4 sv = *reinterpret_cast<const float4*>(&s_in[nb + oc0]);
            const f32x4 dd = ctl ? d1 : d0;
            const float4 bb = ctl ? b2v[1] : b2v[0];
            v[ctl][0] = sv.x + dd[0] + bb.x;
            v[ctl][1] = sv.y + dd[1] + bb.y;
            v[ctl][2] = sv.z + dd[2] + bb.z;
            v[ctl][3] = sv.w + dd[3] + bb.w;
            #pragma unroll
            for (int r = 0; r < 4; ++r) { sum += v[ctl][r]; ssq += v[ctl][r] * v[ctl][r]; }
        }
        sum += __shfl_xor(sum, 16, 64); sum += __shfl_xor(sum, 32, 64);
        ssq += __shfl_xor(ssq, 16, 64); ssq += __shfl_xor(ssq, 32, 64);
        if (ldiv == 0) red[wave][lmod] = make_float2(sum, ssq);
        __syncthreads();
        float ts = 0.f, tq = 0.f;
        #pragma unroll
        for (int w = 0; w < 4; ++w) {
            const float2 rr = red[w][lmod];
            ts += rr.x; tq += rr.y;
        }
        __syncthreads();   // also guards t1t reuse next iteration

        const float mu = ts * (1.0f / HH);
        const float var = tq * (1.0f / HH) - mu * mu;
        const float rs = rsqrtf(var + LN_EPS);

        if (node < N) {
            #pragma unroll
            for (int ctl = 0; ctl < 2; ++ctl) {
                const int oc0 = (2 * wave + ctl) * 16 + ldiv * 4;
                float o[4];
                o[0] = silu((v[ctl][0] - mu) * rs * gv[ctl].x + ev[ctl].x);
                o[1] = silu((v[ctl][1] - mu) * rs * gv[ctl].y + ev[ctl].y);
                o[2] = silu((v[ctl][2] - mu) * rs * gv[ctl].z + ev[ctl].z);
                o[3] = silu((v[ctl][3] - mu) * rs * gv[ctl].w + ev[ctl].w);
                *reinterpret_cast<float4*>(&s_out[nb + oc0]) =
                    make_float4(o[0], o[1], o[2], o[3]);
                uint2 pk;
                pk.x = (unsigned)f2bf(o[0]) | ((unsigned)f2bf(o[1]) << 16);
                pk.y = (unsigned)f2bf(o[2]) | ((unsigned)f2bf(o[3]) << 16);
                *reinterpret_cast<uint2*>(&sb_out[nb + oc0]) = pk;
            }
        }
    }
}

// ---------------------------------------------------------------------------
extern "C" void kernel_launch(void* const* d_in, const int* in_sizes, int n_in,
                              void* d_out, int out_size, void* d_ws, size_t ws_size,
                              hipStream_t stream) {
    const float* s0  = (const float*)d_in[0];
    const int*   ei  = (const int*)  d_in[1];
    const float* ea  = (const float*)d_in[2];
    const float* We  = (const float*)d_in[3];
    const float* be  = (const float*)d_in[4];
    const float* W1  = (const float*)d_in[5];
    const float* b1  = (const float*)d_in[6];
    const float* W2  = (const float*)d_in[7];
    const float* b2  = (const float*)d_in[8];
    const float* gm  = (const float*)d_in[9];
    const float* bt  = (const float*)d_in[10];

    const int NH = in_sizes[0];          // N * 128
    const int N  = NH / HH;
    const int E  = in_sizes[1] / 2;
    const int* src = ei;
    const int* dst = ei + E;

    // ws layout
    float*          sbuf  = (float*)d_ws;                       // [N*H] f32
    unsigned short* sb    = (unsigned short*)(sbuf + NH);       // [N*H] bf16 shadow
    unsigned short* hb16  = sb + NH;                            // [N*H] bf16 h
    unsigned short* ea_b  = hb16 + NH;                          // [E*64] bf16
    bf16x8*         WeB   = (bf16x8*)(ea_b + (size_t)E * EDD);  // [3*16*64]
    bf16x8*         W1B   = WeB + NLAYER * 16 * 64;             // [3*32*64]
    bf16x8*         W2B   = W1B + NLAYER * 32 * 64;             // [3*32*64]
    int*            src_s = (int*)(W2B + NLAYER * 32 * 64);     // [E+16]
    int*            eid_s = src_s + (E + 16);                   // [E+16]
    int*            off   = eid_s + (E + 16);                   // [N+1]
    int*            cursor= off + (N + 1);                      // [N] (also cnt)

    hipMemcpyAsync(sbuf, s0, sizeof(float) * NH, hipMemcpyDeviceToDevice, stream);

    // ---- one-time preprocessing
    hipMemsetAsync(cursor, 0, sizeof(int) * N, stream);
    hist_kernel<<<1024, 256, 0, stream>>>(dst, cursor, E);
    scan_kernel<<<1, 1024, 0, stream>>>(cursor, off, N);
    hipMemcpyAsync(cursor, off, sizeof(int) * N, hipMemcpyDeviceToDevice, stream);
    scatter2_kernel<<<1024, 256, 0, stream>>>(src, dst, cursor, src_s, eid_s, E);
    conv_ea<<<2048, 256, 0, stream>>>(ea, ea_b, (long long)E * EDD / 4);
    conv_s<<<1024, 256, 0, stream>>>(s0, (unsigned int*)sb, (long long)NH / 4);
    prep_we<<<12, 256, 0, stream>>>(We, WeB);
    prep_w128<<<24, 256, 0, stream>>>(W1, W1B);
    prep_w128<<<24, 256, 0, stream>>>(W2, W2B);

    for (int l = 0; l < NLAYER; ++l) {
        gine_agg_mfma<<<4096, 256, 0, stream>>>(sbuf, sb, src_s, eid_s, off, ea_b,
                                                WeB + (size_t)l * 16 * 64,
                                                be + l * HH, hb16, N, E);
        float* sout = (l == NLAYER - 1) ? (float*)d_out : sbuf;
        gine_mlp<<<2048, 256, 0, stream>>>(sbuf, hb16,
                                           W1B + (size_t)l * 32 * 64, b1 + l * HH,
                                           W2B + (size_t)l * 32 * 64, b2 + l * HH,
                                           gm + l * HH, bt + l * HH,
                                           sout, sb, N);
    }
}